// Round 9
// baseline (231.591 us; speedup 1.0000x reference)
//
#include <hip/hip_runtime.h>

#define NB 1024
#define NR 100

typedef _Float16 half_t;
typedef half_t f16x8 __attribute__((ext_vector_type(8)));
typedef float f32x4 __attribute__((ext_vector_type(4)));

__device__ __forceinline__ int kmap2(int g, int j) {
    return g*4 + (j & 3) + ((j >> 2) << 4);
}

// packed f32 fma helper: c += a * splat(s)   (targets v_pk_fma_f32)
__device__ __forceinline__ float2 pkfma(float2 a, float s, float2 c) {
    c.x = fmaf(a.x, s, c.x);
    c.y = fmaf(a.y, s, c.y);
    return c;
}

// async global->LDS, 16B per lane; LDS dest = base + lane*16 (HW behavior)
#define GLDS(gsrc, ldst) \
    __builtin_amdgcn_global_load_lds( \
        (const __attribute__((address_space(1))) void*)(gsrc), \
        (__attribute__((address_space(3))) void*)(ldst), 16, 0, 0)

// ---------------------------------------------------------------------------
// wpack: conv weights -> oc-pair-packed float2 arrays.
// wp1[k][g][2]   (k=ky*3+kx 0..8, g=0..2, pair {w[2g][k], w[2g+1][k]})
// wp2[ocg][216][2] (pair {w[2ocg][k], w[2ocg+1][k]}, k = ic*36+ky*6+kx)
// ---------------------------------------------------------------------------
__global__ __launch_bounds__(256) void wpack_k(
        const float* __restrict__ c1w, const float* __restrict__ c2w,
        float* __restrict__ wp1, float* __restrict__ wp2) {
    const int t = threadIdx.x;
    if (t < 27) {
        const int k = t / 3, g = t - (t/3)*3;
        wp1[t*2+0] = c1w[(g*2+0)*9 + k];
        wp1[t*2+1] = c1w[(g*2+1)*9 + k];
    }
    for (int i = t; i < 432; i += 256) {
        const int ocg = i / 216, k = i - ocg*216;
        wp2[i*2+0] = c2w[(ocg*2+0)*216 + k];
        wp2[i*2+1] = c2w[(ocg*2+1)*216 + k];
    }
}

// ---------------------------------------------------------------------------
// conv1 v2: x[B,1,98,98] -> out[B,6,49,49]  (3x3 pad1 + relu + maxpool2)
// oc-pair packed f32 math; weight pairs via uniform s_load_dwordx2.
// ---------------------------------------------------------------------------
__global__ __launch_bounds__(256) void conv1_k(const float* __restrict__ x,
        const float* __restrict__ wp1, const float* __restrict__ bias,
        float* __restrict__ out) {
    __shared__ float img[98*98];
    const int b = blockIdx.x;
    const int tid = threadIdx.x;
    const float* xb = x + (size_t)b * 9604;
    for (int i = tid; i < 2401; i += 256)
        ((float4*)img)[i] = ((const float4*)xb)[i];
    __syncthreads();
    for (int pos = tid; pos < 2401; pos += 256) {
        const int py = pos / 49, px = pos % 49;
        const int y0 = 2*py - 1, x0 = 2*px - 1;
        float p[4][4];
        #pragma unroll
        for (int dy = 0; dy < 4; ++dy) {
            const int iy = y0 + dy;
            #pragma unroll
            for (int dx = 0; dx < 4; ++dx) {
                const int ix = x0 + dx;
                p[dy][dx] = (iy >= 0 && iy < 98 && ix >= 0 && ix < 98)
                            ? img[iy*98 + ix] : 0.f;
            }
        }
        float2 a2[3][4];
        #pragma unroll
        for (int g = 0; g < 3; ++g) {
            const float2 bv = *(const float2*)(bias + g*2);
            a2[g][0] = a2[g][1] = a2[g][2] = a2[g][3] = bv;
        }
        #pragma unroll
        for (int ky = 0; ky < 3; ++ky)
            #pragma unroll
            for (int kx = 0; kx < 3; ++kx) {
                const int k = ky*3 + kx;
                const float q0 = p[ky  ][kx], q1 = p[ky  ][kx+1];
                const float q2 = p[ky+1][kx], q3 = p[ky+1][kx+1];
                #pragma unroll
                for (int g = 0; g < 3; ++g) {
                    const float2 wv = *(const float2*)(wp1 + (k*3+g)*2);
                    a2[g][0] = pkfma(wv, q0, a2[g][0]);
                    a2[g][1] = pkfma(wv, q1, a2[g][1]);
                    a2[g][2] = pkfma(wv, q2, a2[g][2]);
                    a2[g][3] = pkfma(wv, q3, a2[g][3]);
                }
            }
        #pragma unroll
        for (int g = 0; g < 3; ++g) {
            const float m0 = fmaxf(fmaxf(a2[g][0].x, a2[g][1].x),
                                   fmaxf(a2[g][2].x, a2[g][3].x));
            const float m1 = fmaxf(fmaxf(a2[g][0].y, a2[g][1].y),
                                   fmaxf(a2[g][2].y, a2[g][3].y));
            out[((size_t)b*6 + g*2    )*2401 + pos] = fmaxf(m0, 0.f);
            out[((size_t)b*6 + g*2 + 1)*2401 + pos] = fmaxf(m1, 0.f);
        }
    }
}

// ---------------------------------------------------------------------------
// conv2 v6: in[B,6,49,49] -> out[B,4,22,22]  (6x6 VALID + relu + pool)
// v4 structure (quadrants, stride-32 swizzled LDS, wave-uniform ocg) with
// oc-pair packed f32 inner loop (weight pairs from wp2 via s_load_dwordx2).
// ---------------------------------------------------------------------------
#define SWZ2(r, c) ((c) ^ ((((r) >> 1) & 3) << 3))

__global__ __launch_bounds__(256, 4) void conv2_k(const float* __restrict__ in,
        const float* __restrict__ wp2, const float* __restrict__ bias,
        float* __restrict__ out) {
    __shared__ float smc[6*27*32];      // 20.25 KB
    const int blk = blockIdx.x;
    const int b  = blk >> 2;
    const int qy = (blk >> 1) & 1, qx = blk & 1;
    const int r0 = qy*22, c0 = qx*22;
    const int tid = threadIdx.x;
    const float* src = in + (size_t)b * 14406;
    {
        const int ty = tid >> 5, tx = tid & 31;   // 8 rows x 32 cols
        if (tx < 27) {
            #pragma unroll
            for (int ic = 0; ic < 6; ++ic)
                for (int rr = ty; rr < 27; rr += 8)
                    smc[ic*864 + rr*32 + SWZ2(rr, tx)] =
                        src[ic*2401 + (size_t)(r0 + rr)*49 + c0 + tx];
        }
    }
    __syncthreads();

    const int wv_ = tid >> 6;
    const int ocg = __builtin_amdgcn_readfirstlane(tid >> 7);  // wave-uniform
    const int unit = ((wv_ & 1) << 6) | (tid & 63);            // 0..127
    if (unit >= 121) return;
    const int py = unit / 11, px = unit - py*11;
    const int y0 = 2*py, x0 = 2*px;

    int aofs[7][4];
    #pragma unroll
    for (int u = 0; u < 7; ++u) {
        const int rr = y0 + u;
        #pragma unroll
        for (int vi = 0; vi < 3; ++vi)
            aofs[u][vi] = (rr*32 + SWZ2(rr, x0 + 2*vi)) * 4;
        aofs[u][3] = (rr*32 + SWZ2(rr, x0 + 6)) * 4;
    }

    const float* wg = wp2 + (size_t)ocg * 432;    // 216 float2 pairs
    float2 acc2[2][2];                            // [dy][dx], packed over oc
    {
        const float2 bv = *(const float2*)(bias + ocg*2);
        acc2[0][0] = acc2[0][1] = acc2[1][0] = acc2[1][1] = bv;
    }

    #pragma unroll
    for (int ic = 0; ic < 6; ++ic) {
        const char* plane = (const char*)smc + ic*3456;
        #pragma unroll
        for (int u = 0; u < 7; ++u) {
            float pr[7];
            *(float2*)&pr[0] = *(const float2*)(plane + aofs[u][0]);
            *(float2*)&pr[2] = *(const float2*)(plane + aofs[u][1]);
            *(float2*)&pr[4] = *(const float2*)(plane + aofs[u][2]);
            pr[6] = *(const float*)(plane + aofs[u][3]);
            #pragma unroll
            for (int dy = 0; dy < 2; ++dy) {
                const int ky = u - dy;
                if (ky < 0 || ky > 5) continue;
                #pragma unroll
                for (int kx = 0; kx < 6; ++kx) {
                    const float2 wv =
                        *(const float2*)(wg + (ic*36 + ky*6 + kx)*2);
                    acc2[dy][0] = pkfma(wv, pr[0+kx], acc2[dy][0]);
                    acc2[dy][1] = pkfma(wv, pr[1+kx], acc2[dy][1]);
                }
            }
        }
    }

    const int PY = qy*11 + py, PX = qx*11 + px;
    {
        const float m0 = fmaxf(fmaxf(acc2[0][0].x, acc2[0][1].x),
                               fmaxf(acc2[1][0].x, acc2[1][1].x));
        const float m1 = fmaxf(fmaxf(acc2[0][0].y, acc2[0][1].y),
                               fmaxf(acc2[1][0].y, acc2[1][1].y));
        out[(((size_t)b*4 + ocg*2    )*22 + PY)*22 + PX] = fmaxf(m0, 0.f);
        out[(((size_t)b*4 + ocg*2 + 1)*22 + PY)*22 + PX] = fmaxf(m1, 0.f);
    }
}

// ---------------------------------------------------------------------------
// conv3: in[B,4,22,22] -> out[B,200]
// ---------------------------------------------------------------------------
__global__ __launch_bounds__(256) void conv3_k(const float* __restrict__ in,
        const float* __restrict__ w, const float* __restrict__ bias,
        float* __restrict__ out) {
    __shared__ float sm[1936];
    const int b = blockIdx.x;
    const int tid = threadIdx.x;
    const float* src = in + (size_t)b * 1936;
    for (int i = tid; i < 484; i += 256)
        ((float4*)sm)[i] = ((const float4*)src)[i];
    __syncthreads();
    if (tid < 200) {
        const int c = tid / 100;
        const int rem = tid % 100;
        const int py = rem / 10, px = rem % 10;
        const int y0 = 2*py, x0 = 2*px;
        float a0, a1, a2, a3;
        a0 = a1 = a2 = a3 = bias[c];
        #pragma unroll
        for (int ic = 0; ic < 4; ++ic) {
            float p[4][4];
            const float* base = sm + ic*484 + y0*22 + x0;
            #pragma unroll
            for (int u = 0; u < 4; ++u)
                #pragma unroll
                for (int v = 0; v < 4; ++v)
                    p[u][v] = base[u*22 + v];
            #pragma unroll
            for (int ky = 0; ky < 3; ++ky) {
                #pragma unroll
                for (int kx = 0; kx < 3; ++kx) {
                    const float wv = w[(c*4 + ic)*9 + ky*3 + kx];
                    a0 = fmaf(wv, p[ky  ][kx  ], a0);
                    a1 = fmaf(wv, p[ky  ][kx+1], a1);
                    a2 = fmaf(wv, p[ky+1][kx  ], a2);
                    a3 = fmaf(wv, p[ky+1][kx+1], a3);
                }
            }
        }
        float m = fmaxf(fmaxf(a0, a1), fmaxf(a2, a3));
        out[(size_t)b*200 + tid] = fmaxf(m, 0.f);
    }
}

// ---------------------------------------------------------------------------
// f32 GEMM (fc1 / fc2), 128x64 tile. G0OUT: write packed f16 hi/lo fragment
// planes (B-fragment layout for the head kernel) instead of f32 C.
// ---------------------------------------------------------------------------
template<bool G0OUT>
__global__ __launch_bounds__(256, 4) void gemm_k(
        const float* __restrict__ A, int lda,
        const float* __restrict__ W, const float* __restrict__ bias,
        float* __restrict__ C, int ldc,
        int M, int N, int K,
        half_t* __restrict__ g0h, half_t* __restrict__ g0l) {
    __shared__ float As[32][132];
    __shared__ float Ws[32][64];
    const int m0 = blockIdx.y * 128;
    const int n0 = blockIdx.x * 64;
    const int tid = threadIdx.x;
    const int ti = tid >> 4, tj = tid & 15;
    float acc[8][4];
    #pragma unroll
    for (int i = 0; i < 8; ++i)
        #pragma unroll
        for (int j = 0; j < 4; ++j) acc[i][j] = 0.f;

    for (int k0 = 0; k0 < K; k0 += 32) {
        #pragma unroll
        for (int i = 0; i < 4; ++i) {
            const int f = tid + i*256;
            const int m = f >> 3, kg = f & 7;
            const int kk = kg*4;
            float4 v = make_float4(0.f, 0.f, 0.f, 0.f);
            if (k0 + kk < K)
                v = *(const float4*)(A + (long)(m0 + m)*lda + k0 + kk);
            As[kk+0][m] = v.x;
            As[kk+1][m] = v.y;
            As[kk+2][m] = v.z;
            As[kk+3][m] = v.w;
        }
        #pragma unroll
        for (int i = 0; i < 2; ++i) {
            const int f = tid + i*256;
            const int kk = f >> 4, cg = f & 15;
            const int n = n0 + cg*4;
            float4 v = make_float4(0.f, 0.f, 0.f, 0.f);
            if (k0 + kk < K) {
                const float* wp = W + (long)(k0 + kk)*N;
                if (n + 3 < N) v = *(const float4*)(wp + n);
                else {
                    if (n+0 < N) v.x = wp[n+0];
                    if (n+1 < N) v.y = wp[n+1];
                    if (n+2 < N) v.z = wp[n+2];
                }
            }
            *(float4*)&Ws[kk][cg*4] = v;
        }
        __syncthreads();
        #pragma unroll
        for (int kk = 0; kk < 32; ++kk) {
            float a[8], wv[4];
            *(float4*)&a[0] = *(const float4*)&As[kk][ti*8];
            *(float4*)&a[4] = *(const float4*)&As[kk][ti*8 + 4];
            *(float4*)&wv[0] = *(const float4*)&Ws[kk][tj*4];
            #pragma unroll
            for (int i = 0; i < 8; ++i)
                #pragma unroll
                for (int j = 0; j < 4; ++j)
                    acc[i][j] = fmaf(a[i], wv[j], acc[i][j]);
        }
        __syncthreads();
    }

    const int nb = n0 + tj*4;
    float bv[4] = {0.f, 0.f, 0.f, 0.f};
    #pragma unroll
    for (int e = 0; e < 4; ++e) if (nb + e < N) bv[e] = bias[nb + e];

    if (!G0OUT) {
        #pragma unroll
        for (int i = 0; i < 8; ++i) {
            const long m = m0 + ti*8 + i;
            if (nb + 3 < N) {
                float4 v;
                v.x = fmaxf(acc[i][0] + bv[0], 0.f);
                v.y = fmaxf(acc[i][1] + bv[1], 0.f);
                v.z = fmaxf(acc[i][2] + bv[2], 0.f);
                v.w = fmaxf(acc[i][3] + bv[3], 0.f);
                *(float4*)(C + m*(long)ldc + nb) = v;
            } else {
                #pragma unroll
                for (int j = 0; j < 4; ++j)
                    if (nb + j < N)
                        C[m*(long)ldc + nb + j] = fmaxf(acc[i][j] + bv[j], 0.f);
            }
        }
    } else {
        #pragma unroll
        for (int i = 0; i < 8; ++i) {
            const int m = m0 + ti*8 + i;
            #pragma unroll
            for (int j = 0; j < 4; ++j) {
                const int k = nb + j;
                if (k < N) {
                    const float v = fmaxf(acc[i][j] + bv[j], 0.f);
                    const half_t hi = (half_t)v;
                    const half_t lo = (half_t)(v - (float)hi);
                    const int kc = k >> 5, klo = k & 31;
                    const int h = klo >> 4, rm = klo & 15;
                    const int gg = rm >> 2, rr = rm & 3;
                    const size_t idx =
                        ((size_t)((m >> 4)*7 + kc)*64 + (gg << 4) + (m & 15))*8
                        + h*4 + rr;
                    g0h[idx] = hi;
                    g0l[idx] = lo;
                }
            }
        }
    }
}

// ---------------------------------------------------------------------------
// wsplit: all 4 head weight arrays f32 -> fragment-ordered f16 hi/lo planes.
// ---------------------------------------------------------------------------
__global__ __launch_bounds__(256) void wsplit_k(
        const float* __restrict__ w1, const float* __restrict__ w2,
        const float* __restrict__ w3, const float* __restrict__ w4,
        half_t* __restrict__ f1h, half_t* __restrict__ f1l,
        half_t* __restrict__ f2h, half_t* __restrict__ f2l,
        half_t* __restrict__ f3h, half_t* __restrict__ f3l,
        half_t* __restrict__ f4h, half_t* __restrict__ f4l) {
    __shared__ float lds[32*140];
    const int cx = blockIdx.x, r = blockIdx.y, tid = threadIdx.x;
    int K, N, KC, NF, kc;
    const float* src;
    half_t *dh, *dl;
    if (cx < 7)       { K=200; N=140; KC=7; NF=9; kc=cx;    src=w1; dh=f1h; dl=f1l; }
    else if (cx < 12) { K=140; N=84;  KC=5; NF=6; kc=cx-7;  src=w2; dh=f2h; dl=f2l; }
    else if (cx < 15) { K=84;  N=42;  KC=3; NF=3; kc=cx-12; src=w3; dh=f3h; dl=f3l; }
    else              { K=42;  N=4;   KC=2; NF=1; kc=cx-15; src=w4; dh=f4h; dl=f4l; }
    const float* sb = src + (size_t)r * K * N;
    for (int i = tid; i < 32*N; i += 256) {
        const int kk = i / N, n = i - kk*N;
        const int kg = kc*32 + kk;
        lds[kk*N + n] = (kg < K) ? sb[(size_t)kg*N + n] : 0.f;
    }
    __syncthreads();
    const size_t base = ((size_t)r*KC + kc)*NF*512;
    for (int e = tid; e < NF*512; e += 256) {
        const int nf = e >> 9, rem = e & 511;
        const int l = rem >> 3, j = rem & 7;
        const int g = l >> 4, c = l & 15;
        const int kl = kmap2(g, j);
        const int n = nf*16 + c;
        const float v = (n < N) ? lds[kl*N + n] : 0.f;
        const half_t hi = (half_t)v;
        const half_t lo = (half_t)(v - (float)hi);
        dh[base + (size_t)nf*512 + rem] = hi;
        dl[base + (size_t)nf*512 + rem] = lo;
    }
}

// ---------------------------------------------------------------------------
// head_k v3: fused chain, split-f16 MFMA, single-barrier double-buffered
// LDS weight staging (36 KB ping-pong) + cross-layer prefetch.
// ---------------------------------------------------------------------------
#define MFMA(a, b, c) __builtin_amdgcn_mfma_f32_16x16x32_f16(a, b, c, 0, 0, 0)

__global__ __launch_bounds__(256, 2) void head_k(
        const half_t* __restrict__ g0h, const half_t* __restrict__ g0l,
        const half_t* __restrict__ w1h, const half_t* __restrict__ w1l,
        const half_t* __restrict__ w2h, const half_t* __restrict__ w2l,
        const half_t* __restrict__ w3h, const half_t* __restrict__ w3l,
        const half_t* __restrict__ w4h, const half_t* __restrict__ w4l,
        const float* __restrict__ b1, const float* __restrict__ b2,
        const float* __restrict__ b3, const float* __restrict__ b4,
        float* __restrict__ out) {
    constexpr int CH = 18*512;          // one L1 chunk (9 hi + 9 lo planes)
    __shared__ half_t wb[2*CH];         // 36 KB double buffer
    __shared__ float bl[270];
    const int bid = blockIdx.x;
    const int cx  = bid & 7;
    const int kb  = bid >> 3;
    const int r   = ((kb >> 3) << 3) + cx;
    if (r >= NR) return;
    const int mt  = kb & 7;
    const int tid = threadIdx.x;
    if (tid < 140) bl[tid]       = b1[(size_t)r*140 + tid];
    if (tid < 84)  bl[140 + tid] = b2[(size_t)r*84  + tid];
    if (tid < 42)  bl[224 + tid] = b3[(size_t)r*42  + tid];
    if (tid < 4)   bl[266 + tid] = b4[(size_t)r*4   + tid];
    const int w = tid >> 6, l = tid & 63;
    const int g4 = ((l >> 4) & 3) * 4;
    const int mb0 = mt*8 + w*2;
    const size_t loff = (size_t)l * 8;

    auto stage1 = [&](int kc, half_t* buf) {
        const half_t* hs = w1h + ((size_t)r*7 + kc)*9*512;
        const half_t* ls = w1l + ((size_t)r*7 + kc)*9*512;
        #pragma unroll
        for (int p0 = 0; p0 < 3; ++p0) {
            const int p = w + p0*4;
            if (p < 9) {
                GLDS(hs + (size_t)p*512 + loff, buf + p*512);
                GLDS(ls + (size_t)p*512 + loff, buf + (9+p)*512);
            }
        }
    };
    auto stage2 = [&](int kc, half_t* buf) {
        const half_t* hs = w2h + ((size_t)r*5 + kc)*6*512;
        const half_t* ls = w2l + ((size_t)r*5 + kc)*6*512;
        #pragma unroll
        for (int p0 = 0; p0 < 2; ++p0) {
            const int p = w + p0*4;
            if (p < 6) {
                GLDS(hs + (size_t)p*512 + loff, buf + p*512);
                GLDS(ls + (size_t)p*512 + loff, buf + (6+p)*512);
            }
        }
    };
    auto stage3 = [&](int kc, half_t* buf) {
        const half_t* hs = w3h + ((size_t)r*3 + kc)*3*512;
        const half_t* ls = w3l + ((size_t)r*3 + kc)*3*512;
        if (w < 3) {
            GLDS(hs + (size_t)w*512 + loff, buf + w*512);
            GLDS(ls + (size_t)w*512 + loff, buf + (3+w)*512);
        }
    };

    // ===================== L1: K=200 (7 chunks), N=140 (9 frags) ==========
    f16x8 bhv[2][2], blv[2][2];         // [buf parity][mb]
    stage1(0, wb);
    #pragma unroll
    for (int mb = 0; mb < 2; ++mb) {
        const size_t bo = ((size_t)(mb0 + mb)*7 + 0)*512 + loff;
        bhv[0][mb] = *(const f16x8*)(g0h + bo);
        blv[0][mb] = *(const f16x8*)(g0l + bo);
    }
    __syncthreads();
    f32x4 a1[2][9] = {};
    #pragma unroll
    for (int kc = 0; kc < 7; ++kc) {
        const half_t* cur = wb + (kc & 1)*CH;
        if (kc < 6) {
            stage1(kc+1, wb + ((kc+1) & 1)*CH);
            #pragma unroll
            for (int mb = 0; mb < 2; ++mb) {
                const size_t bo = ((size_t)(mb0 + mb)*7 + kc + 1)*512 + loff;
                bhv[(kc+1)&1][mb] = *(const f16x8*)(g0h + bo);
                blv[(kc+1)&1][mb] = *(const f16x8*)(g0l + bo);
            }
        } else {
            stage2(0, wb + CH);   // kc=6 reads buf0 -> prefetch L2 kc0 to buf1
        }
        #pragma unroll
        for (int nf = 0; nf < 9; ++nf) {
            const f16x8 wh = *(const f16x8*)(cur + nf*512 + loff);
            const f16x8 wl = *(const f16x8*)(cur + (9+nf)*512 + loff);
            #pragma unroll
            for (int mb = 0; mb < 2; ++mb) {
                a1[mb][nf] = MFMA(wh, bhv[kc&1][mb], a1[mb][nf]);
                a1[mb][nf] = MFMA(wh, blv[kc&1][mb], a1[mb][nf]);
                a1[mb][nf] = MFMA(wl, bhv[kc&1][mb], a1[mb][nf]);
            }
        }
        __syncthreads();
    }
    // ---- convert a1 -> L2 B-fragments (bias+relu+split), N1=140 ----
    f16x8 b2h[2][5], b2l[2][5];
    #pragma unroll
    for (int kc = 0; kc < 5; ++kc)
        #pragma unroll
        for (int h = 0; h < 2; ++h) {
            const int nf = kc*2 + h;
            #pragma unroll
            for (int mb = 0; mb < 2; ++mb)
                #pragma unroll
                for (int rr = 0; rr < 4; ++rr) {
                    float v = 0.f;
                    if (nf < 9) {
                        const int n = nf*16 + g4 + rr;
                        v = (n < 140) ? fmaxf(a1[mb][nf][rr] + bl[n], 0.f) : 0.f;
                    }
                    const half_t hi = (half_t)v;
                    const half_t lo = (half_t)(v - (float)hi);
                    b2h[mb][kc][h*4+rr] = hi;
                    b2l[mb][kc][h*4+rr] = lo;
                }
        }
    // ===================== L2: K=140 (5 chunks), N=84 (6 frags) ===========
    // kc0 already staged in buf1; parity: cur(kc) = buf[(kc+1)&1]
    f32x4 a2[2][6] = {};
    #pragma unroll
    for (int kc = 0; kc < 5; ++kc) {
        const half_t* cur = wb + (((kc+1) & 1))*CH;
        if (kc < 4) stage2(kc+1, wb + (kc & 1)*CH);
        else        stage3(0,    wb + (kc & 1)*CH);  // kc=4: cur=buf1
        #pragma unroll
        for (int nf = 0; nf < 6; ++nf) {
            const f16x8 wh = *(const f16x8*)(cur + nf*512 + loff);
            const f16x8 wl = *(const f16x8*)(cur + (6+nf)*512 + loff);
            #pragma unroll
            for (int mb = 0; mb < 2; ++mb) {
                a2[mb][nf] = MFMA(wh, b2h[mb][kc], a2[mb][nf]);
                a2[mb][nf] = MFMA(wh, b2l[mb][kc], a2[mb][nf]);
                a2[mb][nf] = MFMA(wl, b2h[mb][kc], a2[mb][nf]);
            }
        }
        __syncthreads();
    }
    // ---- convert a2 -> L3 B-fragments, N2=84 ----
    f16x8 b3h[2][3], b3l[2][3];
    #pragma unroll
    for (int kc = 0; kc < 3; ++kc)
        #pragma unroll
        for (int h = 0; h < 2; ++h) {
            const int nf = kc*2 + h;
            #pragma unroll
            for (int mb = 0; mb < 2; ++mb)
                #pragma unroll
                for (int rr = 0; rr < 4; ++rr) {
                    float v = 0.f;
                    if (nf < 6) {
                        const int n = nf*16 + g4 + rr;
                        v = (n < 84) ? fmaxf(a2[mb][nf][rr] + bl[140 + n], 0.f) : 0.f;
                    }
                    const half_t hi = (half_t)v;
                    const half_t lo = (half_t)(v - (float)hi);
                    b3h[mb][kc][h*4+rr] = hi;
                    b3l[mb][kc][h*4+rr] = lo;
                }
        }
    // ===================== L3: K=84 (3 chunks), N=42 (3 frags) ============
    // kc0 staged in buf0; cur(kc) = buf[kc&1]
    f32x4 a3[2][3] = {};
    #pragma unroll
    for (int kc = 0; kc < 3; ++kc) {
        const half_t* cur = wb + (kc & 1)*CH;
        if (kc < 2) stage3(kc+1, wb + ((kc+1) & 1)*CH);
        #pragma unroll
        for (int nf = 0; nf < 3; ++nf) {
            const f16x8 wh = *(const f16x8*)(cur + nf*512 + loff);
            const f16x8 wl = *(const f16x8*)(cur + (3+nf)*512 + loff);
            #pragma unroll
            for (int mb = 0; mb < 2; ++mb) {
                a3[mb][nf] = MFMA(wh, b3h[mb][kc], a3[mb][nf]);
                a3[mb][nf] = MFMA(wh, b3l[mb][kc], a3[mb][nf]);
                a3[mb][nf] = MFMA(wl, b3h[mb][kc], a3[mb][nf]);
            }
        }
        __syncthreads();
    }
    // ---- convert a3 -> L4 B-fragments, N3=42 ----
    f16x8 b4h[2][2], b4l[2][2];
    #pragma unroll
    for (int kc = 0; kc < 2; ++kc)
        #pragma unroll
        for (int h = 0; h < 2; ++h) {
            const int nf = kc*2 + h;
            #pragma unroll
            for (int mb = 0; mb < 2; ++mb)
                #pragma unroll
                for (int rr = 0; rr < 4; ++rr) {
                    float v = 0.f;
                    if (nf < 3) {
                        const int n = nf*16 + g4 + rr;
                        v = (n < 42) ? fmaxf(a3[mb][nf][rr] + bl[224 + n], 0.f) : 0.f;
                    }
                    const half_t hi = (half_t)v;
                    const half_t lo = (half_t)(v - (float)hi);
                    b4h[mb][kc][h*4+rr] = hi;
                    b4l[mb][kc][h*4+rr] = lo;
                }
        }
    // ===================== L4: K=42 (2 chunks), N=4 — direct global =======
    f32x4 a4[2] = {};
    #pragma unroll
    for (int kc = 0; kc < 2; ++kc) {
        const size_t wo = ((size_t)r*2 + kc)*512 + loff;
        const f16x8 wh = *(const f16x8*)(w4h + wo);
        const f16x8 wl = *(const f16x8*)(w4l + wo);
        #pragma unroll
        for (int mb = 0; mb < 2; ++mb) {
            a4[mb] = MFMA(wh, b4h[mb][kc], a4[mb]);
            a4[mb] = MFMA(wh, b4l[mb][kc], a4[mb]);
            a4[mb] = MFMA(wl, b4h[mb][kc], a4[mb]);
        }
    }
    if ((l >> 4) == 0) {
        #pragma unroll
        for (int mb = 0; mb < 2; ++mb) {
            const int b = (mb0 + mb)*16 + (l & 15);
            float4 o;
            o.x = a4[mb][0] + bl[266];
            o.y = a4[mb][1] + bl[267];
            o.z = a4[mb][2] + bl[268];
            o.w = a4[mb][3] + bl[269];
            *(float4*)(out + (size_t)b*400 + r*4) = o;
        }
    }
}

extern "C" void kernel_launch(void* const* d_in, const int* in_sizes, int n_in,
                              void* d_out, int out_size, void* d_ws, size_t ws_size,
                              hipStream_t stream) {
    const float* x    = (const float*)d_in[0];
    const float* c1w  = (const float*)d_in[1];
    const float* c1b  = (const float*)d_in[2];
    const float* c2w  = (const float*)d_in[3];
    const float* c2b  = (const float*)d_in[4];
    const float* c3w  = (const float*)d_in[5];
    const float* c3b  = (const float*)d_in[6];
    const float* fc1w = (const float*)d_in[7];
    const float* fc1b = (const float*)d_in[8];
    const float* fc2w = (const float*)d_in[9];
    const float* fc2b = (const float*)d_in[10];
    const float* h1w  = (const float*)d_in[11];
    const float* h1b  = (const float*)d_in[12];
    const float* h2w  = (const float*)d_in[13];
    const float* h2b  = (const float*)d_in[14];
    const float* h3w  = (const float*)d_in[15];
    const float* h3b  = (const float*)d_in[16];
    const float* h4w  = (const float*)d_in[17];
    const float* h4b  = (const float*)d_in[18];
    float* out = (float*)d_out;

    char* ws = (char*)d_ws;
    size_t o = 0;
    float* t1 = (float*)(ws + o); o += (size_t)NB*6*2401*4;
    float* t2 = (float*)(ws + o); o += (size_t)NB*4*484*4;
    float* t3 = (float*)(ws + o); o += (size_t)NB*200*4;
    float* f1 = (float*)(ws + o); o += (size_t)NB*400*4;
    half_t* g0h = (half_t*)(ws + o); o += (size_t)64*7*512*2;
    half_t* g0l = (half_t*)(ws + o); o += (size_t)64*7*512*2;
    half_t* w1h = (half_t*)(ws + o); o += (size_t)NR*7*9*512*2;
    half_t* w1l = (half_t*)(ws + o); o += (size_t)NR*7*9*512*2;
    half_t* w2h = (half_t*)(ws + o); o += (size_t)NR*5*6*512*2;
    half_t* w2l = (half_t*)(ws + o); o += (size_t)NR*5*6*512*2;
    half_t* w3h = (half_t*)(ws + o); o += (size_t)NR*3*3*512*2;
    half_t* w3l = (half_t*)(ws + o); o += (size_t)NR*3*3*512*2;
    half_t* w4h = (half_t*)(ws + o); o += (size_t)NR*2*1*512*2;
    half_t* w4l = (half_t*)(ws + o); o += (size_t)NR*2*1*512*2;
    float* wp1 = (float*)(ws + o); o += 64*4;      // 27 float2 pairs (padded)
    float* wp2 = (float*)(ws + o); o += 896*4;     // 432 float2 pairs (padded)

    hipMemsetAsync(g0h, 0, (size_t)64*7*512*2*2, stream);

    wpack_k<<<1, 256, 0, stream>>>(c1w, c2w, wp1, wp2);
    wsplit_k<<<dim3(17, NR), 256, 0, stream>>>(h1w, h2w, h3w, h4w,
        w1h, w1l, w2h, w2l, w3h, w3l, w4h, w4l);

    conv1_k<<<NB, 256, 0, stream>>>(x, wp1, c1b, t1);
    conv2_k<<<NB*4, 256, 0, stream>>>(t1, wp2, c2b, t2);
    conv3_k<<<NB, 256, 0, stream>>>(t2, c3w, c3b, t3);

    gemm_k<false><<<dim3(7, 8), 256, 0, stream>>>(
        t3, 200, fc1w, fc1b, f1, 400, NB, 400, 200, nullptr, nullptr);
    gemm_k<true><<<dim3(4, 8), 256, 0, stream>>>(
        f1, 400, fc2w, fc2b, nullptr, 0, NB, 200, 400, g0h, g0l);

    head_k<<<832, 256, 0, stream>>>(
        g0h, g0l, w1h, w1l, w2h, w2l, w3h, w3l, w4h, w4l,
        h1b, h2b, h3b, h4b, out);

    (void)in_sizes; (void)n_in; (void)out_size; (void)ws_size;
}

// Round 10
// 196.440 us; speedup vs baseline: 1.1789x; 1.1789x over previous
//
#include <hip/hip_runtime.h>

#define NB 1024
#define NR 100

typedef _Float16 half_t;
typedef half_t f16x8 __attribute__((ext_vector_type(8)));
typedef float f32x4 __attribute__((ext_vector_type(4)));
typedef float f32x2 __attribute__((ext_vector_type(2)));

__device__ __forceinline__ int kmap2(int g, int j) {
    return g*4 + (j & 3) + ((j >> 2) << 4);
}

// packed f32 fma: c += a * splat(s)  — elementwise builtin -> v_pk_fma_f32
__device__ __forceinline__ f32x2 pkfma(f32x2 a, float s, f32x2 c) {
    return __builtin_elementwise_fma(a, (f32x2){s, s}, c);
}

// async global->LDS, 16B per lane; LDS dest = base + lane*16 (HW behavior)
#define GLDS(gsrc, ldst) \
    __builtin_amdgcn_global_load_lds( \
        (const __attribute__((address_space(1))) void*)(gsrc), \
        (__attribute__((address_space(3))) void*)(ldst), 16, 0, 0)

#define SWZ2(r, c) ((c) ^ ((((r) >> 1) & 3) << 3))

// ---------------------------------------------------------------------------
// conv12: fused conv1(3x3 pad1 +relu+pool) -> conv2(6x6 VALID +relu+pool).
// One block per image quadrant (4096 blocks). Stages raw input window
// (56x56, stride 57), computes conv1 pooled 27x27x6 into the swizzled
// stride-32 LDS layout, then the conv2 body consumes it (as before).
// Weights oc-pair packed (wp1/wp2), read via uniform scalar loads.
// ---------------------------------------------------------------------------
__global__ __launch_bounds__(256, 4) void conv12_k(const float* __restrict__ x,
        const float* __restrict__ wp1, const float* __restrict__ b1c,
        const float* __restrict__ wp2, const float* __restrict__ b2c,
        float* __restrict__ out) {
    __shared__ float img[56*57];        // 12.77 KB raw input window
    __shared__ float c1o[6*27*32];      // 20.25 KB conv1 pooled (swizzled)
    const int blk = blockIdx.x;
    const int b  = blk >> 2;
    const int qy = (blk >> 1) & 1, qx = blk & 1;
    const int R0 = 44*qy - 1, C0 = 44*qx - 1;   // staged-window origin in x
    const int tid = threadIdx.x;
    const float* xb = x + (size_t)b * 9604;

    for (int i = tid; i < 56*56; i += 256) {
        const int rr = i / 56, cc = i - rr*56;
        const int gr = R0 + rr, gc = C0 + cc;
        float v = 0.f;
        if (gr >= 0 && gr < 98 && gc >= 0 && gc < 98) v = xb[gr*98 + gc];
        img[rr*57 + cc] = v;
    }
    __syncthreads();

    // ---- conv1 part: pooled (py,px) local 0..26, patch img[2py..+3][2px..+3]
    for (int pos = tid; pos < 729; pos += 256) {
        const int py = pos / 27, px = pos - py*27;
        float p[4][4];
        const float* base = img + (2*py)*57 + 2*px;
        #pragma unroll
        for (int u = 0; u < 4; ++u)
            #pragma unroll
            for (int v = 0; v < 4; ++v)
                p[u][v] = base[u*57 + v];
        f32x2 a2[3][4];
        #pragma unroll
        for (int g = 0; g < 3; ++g) {
            const f32x2 bv = *(const f32x2*)(b1c + g*2);
            a2[g][0] = a2[g][1] = a2[g][2] = a2[g][3] = bv;
        }
        #pragma unroll
        for (int ky = 0; ky < 3; ++ky)
            #pragma unroll
            for (int kx = 0; kx < 3; ++kx) {
                const int k = ky*3 + kx;
                const float q0 = p[ky  ][kx], q1 = p[ky  ][kx+1];
                const float q2 = p[ky+1][kx], q3 = p[ky+1][kx+1];
                #pragma unroll
                for (int g = 0; g < 3; ++g) {
                    const f32x2 wv = *(const f32x2*)(wp1 + (k*3+g)*2);
                    a2[g][0] = pkfma(wv, q0, a2[g][0]);
                    a2[g][1] = pkfma(wv, q1, a2[g][1]);
                    a2[g][2] = pkfma(wv, q2, a2[g][2]);
                    a2[g][3] = pkfma(wv, q3, a2[g][3]);
                }
            }
        #pragma unroll
        for (int g = 0; g < 3; ++g) {
            const float m0 = fmaxf(fmaxf(a2[g][0].x, a2[g][1].x),
                                   fmaxf(a2[g][2].x, a2[g][3].x));
            const float m1 = fmaxf(fmaxf(a2[g][0].y, a2[g][1].y),
                                   fmaxf(a2[g][2].y, a2[g][3].y));
            const int col = SWZ2(py, px);
            c1o[(g*2    )*864 + py*32 + col] = fmaxf(m0, 0.f);
            c1o[(g*2 + 1)*864 + py*32 + col] = fmaxf(m1, 0.f);
        }
    }
    __syncthreads();

    // ---- conv2 part (body identical to prior conv2_k, reads c1o) ----
    const int wv_ = tid >> 6;
    const int ocg = __builtin_amdgcn_readfirstlane(tid >> 7);  // wave-uniform
    const int unit = ((wv_ & 1) << 6) | (tid & 63);            // 0..127
    if (unit >= 121) return;
    const int py = unit / 11, px = unit - py*11;
    const int y0 = 2*py, x0 = 2*px;

    int aofs[7][4];
    #pragma unroll
    for (int u = 0; u < 7; ++u) {
        const int rr = y0 + u;
        #pragma unroll
        for (int vi = 0; vi < 3; ++vi)
            aofs[u][vi] = (rr*32 + SWZ2(rr, x0 + 2*vi)) * 4;
        aofs[u][3] = (rr*32 + SWZ2(rr, x0 + 6)) * 4;
    }

    const float* wg = wp2 + (size_t)ocg * 432;    // 216 f32x2 pairs
    f32x2 acc2[2][2];
    {
        const f32x2 bv = *(const f32x2*)(b2c + ocg*2);
        acc2[0][0] = acc2[0][1] = acc2[1][0] = acc2[1][1] = bv;
    }

    #pragma unroll
    for (int ic = 0; ic < 6; ++ic) {
        const char* plane = (const char*)c1o + ic*3456;
        #pragma unroll
        for (int u = 0; u < 7; ++u) {
            float pr[7];
            *(f32x2*)&pr[0] = *(const f32x2*)(plane + aofs[u][0]);
            *(f32x2*)&pr[2] = *(const f32x2*)(plane + aofs[u][1]);
            *(f32x2*)&pr[4] = *(const f32x2*)(plane + aofs[u][2]);
            pr[6] = *(const float*)(plane + aofs[u][3]);
            #pragma unroll
            for (int dy = 0; dy < 2; ++dy) {
                const int ky = u - dy;
                if (ky < 0 || ky > 5) continue;
                #pragma unroll
                for (int kx = 0; kx < 6; ++kx) {
                    const f32x2 wv =
                        *(const f32x2*)(wg + (ic*36 + ky*6 + kx)*2);
                    acc2[dy][0] = pkfma(wv, pr[0+kx], acc2[dy][0]);
                    acc2[dy][1] = pkfma(wv, pr[1+kx], acc2[dy][1]);
                }
            }
        }
    }

    const int PY = qy*11 + py, PX = qx*11 + px;
    {
        const float m0 = fmaxf(fmaxf(acc2[0][0].x, acc2[0][1].x),
                               fmaxf(acc2[1][0].x, acc2[1][1].x));
        const float m1 = fmaxf(fmaxf(acc2[0][0].y, acc2[0][1].y),
                               fmaxf(acc2[1][0].y, acc2[1][1].y));
        out[(((size_t)b*4 + ocg*2    )*22 + PY)*22 + PX] = fmaxf(m0, 0.f);
        out[(((size_t)b*4 + ocg*2 + 1)*22 + PY)*22 + PX] = fmaxf(m1, 0.f);
    }
}

// ---------------------------------------------------------------------------
// conv3: in[B,4,22,22] -> out[B,200]
// ---------------------------------------------------------------------------
__global__ __launch_bounds__(256) void conv3_k(const float* __restrict__ in,
        const float* __restrict__ w, const float* __restrict__ bias,
        float* __restrict__ out) {
    __shared__ float sm[1936];
    const int b = blockIdx.x;
    const int tid = threadIdx.x;
    const float* src = in + (size_t)b * 1936;
    for (int i = tid; i < 484; i += 256)
        ((float4*)sm)[i] = ((const float4*)src)[i];
    __syncthreads();
    if (tid < 200) {
        const int c = tid / 100;
        const int rem = tid % 100;
        const int py = rem / 10, px = rem % 10;
        const int y0 = 2*py, x0 = 2*px;
        float a0, a1, a2, a3;
        a0 = a1 = a2 = a3 = bias[c];
        #pragma unroll
        for (int ic = 0; ic < 4; ++ic) {
            float p[4][4];
            const float* base = sm + ic*484 + y0*22 + x0;
            #pragma unroll
            for (int u = 0; u < 4; ++u)
                #pragma unroll
                for (int v = 0; v < 4; ++v)
                    p[u][v] = base[u*22 + v];
            #pragma unroll
            for (int ky = 0; ky < 3; ++ky) {
                #pragma unroll
                for (int kx = 0; kx < 3; ++kx) {
                    const float wv = w[(c*4 + ic)*9 + ky*3 + kx];
                    a0 = fmaf(wv, p[ky  ][kx  ], a0);
                    a1 = fmaf(wv, p[ky  ][kx+1], a1);
                    a2 = fmaf(wv, p[ky+1][kx  ], a2);
                    a3 = fmaf(wv, p[ky+1][kx+1], a3);
                }
            }
        }
        float m = fmaxf(fmaxf(a0, a1), fmaxf(a2, a3));
        out[(size_t)b*200 + tid] = fmaxf(m, 0.f);
    }
}

// ---------------------------------------------------------------------------
// f32 GEMM (fc1 / fc2), 128x64 tile. G0OUT: write packed f16 hi/lo fragment
// planes (B-fragment layout for the head kernel) instead of f32 C.
// ---------------------------------------------------------------------------
template<bool G0OUT>
__global__ __launch_bounds__(256, 4) void gemm_k(
        const float* __restrict__ A, int lda,
        const float* __restrict__ W, const float* __restrict__ bias,
        float* __restrict__ C, int ldc,
        int M, int N, int K,
        half_t* __restrict__ g0h, half_t* __restrict__ g0l) {
    __shared__ float As[32][132];
    __shared__ float Ws[32][64];
    const int m0 = blockIdx.y * 128;
    const int n0 = blockIdx.x * 64;
    const int tid = threadIdx.x;
    const int ti = tid >> 4, tj = tid & 15;
    float acc[8][4];
    #pragma unroll
    for (int i = 0; i < 8; ++i)
        #pragma unroll
        for (int j = 0; j < 4; ++j) acc[i][j] = 0.f;

    for (int k0 = 0; k0 < K; k0 += 32) {
        #pragma unroll
        for (int i = 0; i < 4; ++i) {
            const int f = tid + i*256;
            const int m = f >> 3, kg = f & 7;
            const int kk = kg*4;
            float4 v = make_float4(0.f, 0.f, 0.f, 0.f);
            if (k0 + kk < K)
                v = *(const float4*)(A + (long)(m0 + m)*lda + k0 + kk);
            As[kk+0][m] = v.x;
            As[kk+1][m] = v.y;
            As[kk+2][m] = v.z;
            As[kk+3][m] = v.w;
        }
        #pragma unroll
        for (int i = 0; i < 2; ++i) {
            const int f = tid + i*256;
            const int kk = f >> 4, cg = f & 15;
            const int n = n0 + cg*4;
            float4 v = make_float4(0.f, 0.f, 0.f, 0.f);
            if (k0 + kk < K) {
                const float* wp = W + (long)(k0 + kk)*N;
                if (n + 3 < N) v = *(const float4*)(wp + n);
                else {
                    if (n+0 < N) v.x = wp[n+0];
                    if (n+1 < N) v.y = wp[n+1];
                    if (n+2 < N) v.z = wp[n+2];
                }
            }
            *(float4*)&Ws[kk][cg*4] = v;
        }
        __syncthreads();
        #pragma unroll
        for (int kk = 0; kk < 32; ++kk) {
            float a[8], wv[4];
            *(float4*)&a[0] = *(const float4*)&As[kk][ti*8];
            *(float4*)&a[4] = *(const float4*)&As[kk][ti*8 + 4];
            *(float4*)&wv[0] = *(const float4*)&Ws[kk][tj*4];
            #pragma unroll
            for (int i = 0; i < 8; ++i)
                #pragma unroll
                for (int j = 0; j < 4; ++j)
                    acc[i][j] = fmaf(a[i], wv[j], acc[i][j]);
        }
        __syncthreads();
    }

    const int nb = n0 + tj*4;
    float bv[4] = {0.f, 0.f, 0.f, 0.f};
    #pragma unroll
    for (int e = 0; e < 4; ++e) if (nb + e < N) bv[e] = bias[nb + e];

    if (!G0OUT) {
        #pragma unroll
        for (int i = 0; i < 8; ++i) {
            const long m = m0 + ti*8 + i;
            if (nb + 3 < N) {
                float4 v;
                v.x = fmaxf(acc[i][0] + bv[0], 0.f);
                v.y = fmaxf(acc[i][1] + bv[1], 0.f);
                v.z = fmaxf(acc[i][2] + bv[2], 0.f);
                v.w = fmaxf(acc[i][3] + bv[3], 0.f);
                *(float4*)(C + m*(long)ldc + nb) = v;
            } else {
                #pragma unroll
                for (int j = 0; j < 4; ++j)
                    if (nb + j < N)
                        C[m*(long)ldc + nb + j] = fmaxf(acc[i][j] + bv[j], 0.f);
            }
        }
    } else {
        #pragma unroll
        for (int i = 0; i < 8; ++i) {
            const int m = m0 + ti*8 + i;
            #pragma unroll
            for (int j = 0; j < 4; ++j) {
                const int k = nb + j;
                if (k < N) {
                    const float v = fmaxf(acc[i][j] + bv[j], 0.f);
                    const half_t hi = (half_t)v;
                    const half_t lo = (half_t)(v - (float)hi);
                    const int kc = k >> 5, klo = k & 31;
                    const int h = klo >> 4, rm = klo & 15;
                    const int gg = rm >> 2, rr = rm & 3;
                    const size_t idx =
                        ((size_t)((m >> 4)*7 + kc)*64 + (gg << 4) + (m & 15))*8
                        + h*4 + rr;
                    g0h[idx] = hi;
                    g0l[idx] = lo;
                }
            }
        }
    }
}

// ---------------------------------------------------------------------------
// wsplit (+wpack merged at cx==17): head weights -> f16 hi/lo fragment
// planes; conv weights -> oc-pair packed arrays.
// ---------------------------------------------------------------------------
__global__ __launch_bounds__(256) void wsplit_k(
        const float* __restrict__ w1, const float* __restrict__ w2,
        const float* __restrict__ w3, const float* __restrict__ w4,
        half_t* __restrict__ f1h, half_t* __restrict__ f1l,
        half_t* __restrict__ f2h, half_t* __restrict__ f2l,
        half_t* __restrict__ f3h, half_t* __restrict__ f3l,
        half_t* __restrict__ f4h, half_t* __restrict__ f4l,
        const float* __restrict__ c1w, const float* __restrict__ c2w,
        float* __restrict__ wp1, float* __restrict__ wp2) {
    __shared__ float lds[32*140];
    const int cx = blockIdx.x, r = blockIdx.y, tid = threadIdx.x;
    if (cx == 17) {                       // wpack (one block total)
        if (r != 0) return;
        if (tid < 27) {
            const int k = tid / 3, g = tid - (tid/3)*3;
            wp1[tid*2+0] = c1w[(g*2+0)*9 + k];
            wp1[tid*2+1] = c1w[(g*2+1)*9 + k];
        }
        for (int i = tid; i < 432; i += 256) {
            const int ocg = i / 216, k = i - ocg*216;
            wp2[i*2+0] = c2w[(ocg*2+0)*216 + k];
            wp2[i*2+1] = c2w[(ocg*2+1)*216 + k];
        }
        return;
    }
    int K, N, KC, NF, kc;
    const float* src;
    half_t *dh, *dl;
    if (cx < 7)       { K=200; N=140; KC=7; NF=9; kc=cx;    src=w1; dh=f1h; dl=f1l; }
    else if (cx < 12) { K=140; N=84;  KC=5; NF=6; kc=cx-7;  src=w2; dh=f2h; dl=f2l; }
    else if (cx < 15) { K=84;  N=42;  KC=3; NF=3; kc=cx-12; src=w3; dh=f3h; dl=f3l; }
    else              { K=42;  N=4;   KC=2; NF=1; kc=cx-15; src=w4; dh=f4h; dl=f4l; }
    const float* sb = src + (size_t)r * K * N;
    for (int i = tid; i < 32*N; i += 256) {
        const int kk = i / N, n = i - kk*N;
        const int kg = kc*32 + kk;
        lds[kk*N + n] = (kg < K) ? sb[(size_t)kg*N + n] : 0.f;
    }
    __syncthreads();
    const size_t base = ((size_t)r*KC + kc)*NF*512;
    for (int e = tid; e < NF*512; e += 256) {
        const int nf = e >> 9, rem = e & 511;
        const int l = rem >> 3, j = rem & 7;
        const int g = l >> 4, c = l & 15;
        const int kl = kmap2(g, j);
        const int n = nf*16 + c;
        const float v = (n < N) ? lds[kl*N + n] : 0.f;
        const half_t hi = (half_t)v;
        const half_t lo = (half_t)(v - (float)hi);
        dh[base + (size_t)nf*512 + rem] = hi;
        dl[base + (size_t)nf*512 + rem] = lo;
    }
}

// ---------------------------------------------------------------------------
// head_k v3: fused chain, split-f16 MFMA, single-barrier double-buffered
// LDS weight staging (36 KB ping-pong) + cross-layer prefetch.
// ---------------------------------------------------------------------------
#define MFMA(a, b, c) __builtin_amdgcn_mfma_f32_16x16x32_f16(a, b, c, 0, 0, 0)

__global__ __launch_bounds__(256, 2) void head_k(
        const half_t* __restrict__ g0h, const half_t* __restrict__ g0l,
        const half_t* __restrict__ w1h, const half_t* __restrict__ w1l,
        const half_t* __restrict__ w2h, const half_t* __restrict__ w2l,
        const half_t* __restrict__ w3h, const half_t* __restrict__ w3l,
        const half_t* __restrict__ w4h, const half_t* __restrict__ w4l,
        const float* __restrict__ b1, const float* __restrict__ b2,
        const float* __restrict__ b3, const float* __restrict__ b4,
        float* __restrict__ out) {
    constexpr int CH = 18*512;          // one L1 chunk (9 hi + 9 lo planes)
    __shared__ half_t wb[2*CH];         // 36 KB double buffer
    __shared__ float bl[270];
    const int bid = blockIdx.x;
    const int cx  = bid & 7;
    const int kb  = bid >> 3;
    const int r   = ((kb >> 3) << 3) + cx;
    if (r >= NR) return;
    const int mt  = kb & 7;
    const int tid = threadIdx.x;
    if (tid < 140) bl[tid]       = b1[(size_t)r*140 + tid];
    if (tid < 84)  bl[140 + tid] = b2[(size_t)r*84  + tid];
    if (tid < 42)  bl[224 + tid] = b3[(size_t)r*42  + tid];
    if (tid < 4)   bl[266 + tid] = b4[(size_t)r*4   + tid];
    const int w = tid >> 6, l = tid & 63;
    const int g4 = ((l >> 4) & 3) * 4;
    const int mb0 = mt*8 + w*2;
    const size_t loff = (size_t)l * 8;

    auto stage1 = [&](int kc, half_t* buf) {
        const half_t* hs = w1h + ((size_t)r*7 + kc)*9*512;
        const half_t* ls = w1l + ((size_t)r*7 + kc)*9*512;
        #pragma unroll
        for (int p0 = 0; p0 < 3; ++p0) {
            const int p = w + p0*4;
            if (p < 9) {
                GLDS(hs + (size_t)p*512 + loff, buf + p*512);
                GLDS(ls + (size_t)p*512 + loff, buf + (9+p)*512);
            }
        }
    };
    auto stage2 = [&](int kc, half_t* buf) {
        const half_t* hs = w2h + ((size_t)r*5 + kc)*6*512;
        const half_t* ls = w2l + ((size_t)r*5 + kc)*6*512;
        #pragma unroll
        for (int p0 = 0; p0 < 2; ++p0) {
            const int p = w + p0*4;
            if (p < 6) {
                GLDS(hs + (size_t)p*512 + loff, buf + p*512);
                GLDS(ls + (size_t)p*512 + loff, buf + (6+p)*512);
            }
        }
    };
    auto stage3 = [&](int kc, half_t* buf) {
        const half_t* hs = w3h + ((size_t)r*3 + kc)*3*512;
        const half_t* ls = w3l + ((size_t)r*3 + kc)*3*512;
        if (w < 3) {
            GLDS(hs + (size_t)w*512 + loff, buf + w*512);
            GLDS(ls + (size_t)w*512 + loff, buf + (3+w)*512);
        }
    };

    // ===================== L1: K=200 (7 chunks), N=140 (9 frags) ==========
    f16x8 bhv[2][2], blv[2][2];         // [buf parity][mb]
    stage1(0, wb);
    #pragma unroll
    for (int mb = 0; mb < 2; ++mb) {
        const size_t bo = ((size_t)(mb0 + mb)*7 + 0)*512 + loff;
        bhv[0][mb] = *(const f16x8*)(g0h + bo);
        blv[0][mb] = *(const f16x8*)(g0l + bo);
    }
    __syncthreads();
    f32x4 a1[2][9] = {};
    #pragma unroll
    for (int kc = 0; kc < 7; ++kc) {
        const half_t* cur = wb + (kc & 1)*CH;
        if (kc < 6) {
            stage1(kc+1, wb + ((kc+1) & 1)*CH);
            #pragma unroll
            for (int mb = 0; mb < 2; ++mb) {
                const size_t bo = ((size_t)(mb0 + mb)*7 + kc + 1)*512 + loff;
                bhv[(kc+1)&1][mb] = *(const f16x8*)(g0h + bo);
                blv[(kc+1)&1][mb] = *(const f16x8*)(g0l + bo);
            }
        } else {
            stage2(0, wb + CH);   // kc=6 reads buf0 -> prefetch L2 kc0 to buf1
        }
        #pragma unroll
        for (int nf = 0; nf < 9; ++nf) {
            const f16x8 wh = *(const f16x8*)(cur + nf*512 + loff);
            const f16x8 wl = *(const f16x8*)(cur + (9+nf)*512 + loff);
            #pragma unroll
            for (int mb = 0; mb < 2; ++mb) {
                a1[mb][nf] = MFMA(wh, bhv[kc&1][mb], a1[mb][nf]);
                a1[mb][nf] = MFMA(wh, blv[kc&1][mb], a1[mb][nf]);
                a1[mb][nf] = MFMA(wl, bhv[kc&1][mb], a1[mb][nf]);
            }
        }
        __syncthreads();
    }
    // ---- convert a1 -> L2 B-fragments (bias+relu+split), N1=140 ----
    f16x8 b2h[2][5], b2l[2][5];
    #pragma unroll
    for (int kc = 0; kc < 5; ++kc)
        #pragma unroll
        for (int h = 0; h < 2; ++h) {
            const int nf = kc*2 + h;
            #pragma unroll
            for (int mb = 0; mb < 2; ++mb)
                #pragma unroll
                for (int rr = 0; rr < 4; ++rr) {
                    float v = 0.f;
                    if (nf < 9) {
                        const int n = nf*16 + g4 + rr;
                        v = (n < 140) ? fmaxf(a1[mb][nf][rr] + bl[n], 0.f) : 0.f;
                    }
                    const half_t hi = (half_t)v;
                    const half_t lo = (half_t)(v - (float)hi);
                    b2h[mb][kc][h*4+rr] = hi;
                    b2l[mb][kc][h*4+rr] = lo;
                }
        }
    // ===================== L2: K=140 (5 chunks), N=84 (6 frags) ===========
    f32x4 a2[2][6] = {};
    #pragma unroll
    for (int kc = 0; kc < 5; ++kc) {
        const half_t* cur = wb + (((kc+1) & 1))*CH;
        if (kc < 4) stage2(kc+1, wb + (kc & 1)*CH);
        else        stage3(0,    wb + (kc & 1)*CH);
        #pragma unroll
        for (int nf = 0; nf < 6; ++nf) {
            const f16x8 wh = *(const f16x8*)(cur + nf*512 + loff);
            const f16x8 wl = *(const f16x8*)(cur + (6+nf)*512 + loff);
            #pragma unroll
            for (int mb = 0; mb < 2; ++mb) {
                a2[mb][nf] = MFMA(wh, b2h[mb][kc], a2[mb][nf]);
                a2[mb][nf] = MFMA(wh, b2l[mb][kc], a2[mb][nf]);
                a2[mb][nf] = MFMA(wl, b2h[mb][kc], a2[mb][nf]);
            }
        }
        __syncthreads();
    }
    // ---- convert a2 -> L3 B-fragments, N2=84 ----
    f16x8 b3h[2][3], b3l[2][3];
    #pragma unroll
    for (int kc = 0; kc < 3; ++kc)
        #pragma unroll
        for (int h = 0; h < 2; ++h) {
            const int nf = kc*2 + h;
            #pragma unroll
            for (int mb = 0; mb < 2; ++mb)
                #pragma unroll
                for (int rr = 0; rr < 4; ++rr) {
                    float v = 0.f;
                    if (nf < 6) {
                        const int n = nf*16 + g4 + rr;
                        v = (n < 84) ? fmaxf(a2[mb][nf][rr] + bl[140 + n], 0.f) : 0.f;
                    }
                    const half_t hi = (half_t)v;
                    const half_t lo = (half_t)(v - (float)hi);
                    b3h[mb][kc][h*4+rr] = hi;
                    b3l[mb][kc][h*4+rr] = lo;
                }
        }
    // ===================== L3: K=84 (3 chunks), N=42 (3 frags) ============
    f32x4 a3[2][3] = {};
    #pragma unroll
    for (int kc = 0; kc < 3; ++kc) {
        const half_t* cur = wb + (kc & 1)*CH;
        if (kc < 2) stage3(kc+1, wb + ((kc+1) & 1)*CH);
        #pragma unroll
        for (int nf = 0; nf < 3; ++nf) {
            const f16x8 wh = *(const f16x8*)(cur + nf*512 + loff);
            const f16x8 wl = *(const f16x8*)(cur + (3+nf)*512 + loff);
            #pragma unroll
            for (int mb = 0; mb < 2; ++mb) {
                a3[mb][nf] = MFMA(wh, b3h[mb][kc], a3[mb][nf]);
                a3[mb][nf] = MFMA(wh, b3l[mb][kc], a3[mb][nf]);
                a3[mb][nf] = MFMA(wl, b3h[mb][kc], a3[mb][nf]);
            }
        }
        __syncthreads();
    }
    // ---- convert a3 -> L4 B-fragments, N3=42 ----
    f16x8 b4h[2][2], b4l[2][2];
    #pragma unroll
    for (int kc = 0; kc < 2; ++kc)
        #pragma unroll
        for (int h = 0; h < 2; ++h) {
            const int nf = kc*2 + h;
            #pragma unroll
            for (int mb = 0; mb < 2; ++mb)
                #pragma unroll
                for (int rr = 0; rr < 4; ++rr) {
                    float v = 0.f;
                    if (nf < 3) {
                        const int n = nf*16 + g4 + rr;
                        v = (n < 42) ? fmaxf(a3[mb][nf][rr] + bl[224 + n], 0.f) : 0.f;
                    }
                    const half_t hi = (half_t)v;
                    const half_t lo = (half_t)(v - (float)hi);
                    b4h[mb][kc][h*4+rr] = hi;
                    b4l[mb][kc][h*4+rr] = lo;
                }
        }
    // ===================== L4: K=42 (2 chunks), N=4 — direct global =======
    f32x4 a4[2] = {};
    #pragma unroll
    for (int kc = 0; kc < 2; ++kc) {
        const size_t wo = ((size_t)r*2 + kc)*512 + loff;
        const f16x8 wh = *(const f16x8*)(w4h + wo);
        const f16x8 wl = *(const f16x8*)(w4l + wo);
        #pragma unroll
        for (int mb = 0; mb < 2; ++mb) {
            a4[mb] = MFMA(wh, b4h[mb][kc], a4[mb]);
            a4[mb] = MFMA(wh, b4l[mb][kc], a4[mb]);
            a4[mb] = MFMA(wl, b4h[mb][kc], a4[mb]);
        }
    }
    if ((l >> 4) == 0) {
        #pragma unroll
        for (int mb = 0; mb < 2; ++mb) {
            const int b = (mb0 + mb)*16 + (l & 15);
            float4 o;
            o.x = a4[mb][0] + bl[266];
            o.y = a4[mb][1] + bl[267];
            o.z = a4[mb][2] + bl[268];
            o.w = a4[mb][3] + bl[269];
            *(float4*)(out + (size_t)b*400 + r*4) = o;
        }
    }
}

extern "C" void kernel_launch(void* const* d_in, const int* in_sizes, int n_in,
                              void* d_out, int out_size, void* d_ws, size_t ws_size,
                              hipStream_t stream) {
    const float* x    = (const float*)d_in[0];
    const float* c1w  = (const float*)d_in[1];
    const float* c1b  = (const float*)d_in[2];
    const float* c2w  = (const float*)d_in[3];
    const float* c2b  = (const float*)d_in[4];
    const float* c3w  = (const float*)d_in[5];
    const float* c3b  = (const float*)d_in[6];
    const float* fc1w = (const float*)d_in[7];
    const float* fc1b = (const float*)d_in[8];
    const float* fc2w = (const float*)d_in[9];
    const float* fc2b = (const float*)d_in[10];
    const float* h1w  = (const float*)d_in[11];
    const float* h1b  = (const float*)d_in[12];
    const float* h2w  = (const float*)d_in[13];
    const float* h2b  = (const float*)d_in[14];
    const float* h3w  = (const float*)d_in[15];
    const float* h3b  = (const float*)d_in[16];
    const float* h4w  = (const float*)d_in[17];
    const float* h4b  = (const float*)d_in[18];
    float* out = (float*)d_out;

    char* ws = (char*)d_ws;
    size_t o = 0;
    float* t2 = (float*)(ws + o); o += (size_t)NB*4*484*4;
    float* t3 = (float*)(ws + o); o += (size_t)NB*200*4;
    float* f1 = (float*)(ws + o); o += (size_t)NB*400*4;
    half_t* g0h = (half_t*)(ws + o); o += (size_t)64*7*512*2;
    half_t* g0l = (half_t*)(ws + o); o += (size_t)64*7*512*2;
    half_t* w1h = (half_t*)(ws + o); o += (size_t)NR*7*9*512*2;
    half_t* w1l = (half_t*)(ws + o); o += (size_t)NR*7*9*512*2;
    half_t* w2h = (half_t*)(ws + o); o += (size_t)NR*5*6*512*2;
    half_t* w2l = (half_t*)(ws + o); o += (size_t)NR*5*6*512*2;
    half_t* w3h = (half_t*)(ws + o); o += (size_t)NR*3*3*512*2;
    half_t* w3l = (half_t*)(ws + o); o += (size_t)NR*3*3*512*2;
    half_t* w4h = (half_t*)(ws + o); o += (size_t)NR*2*1*512*2;
    half_t* w4l = (half_t*)(ws + o); o += (size_t)NR*2*1*512*2;
    float* wp1 = (float*)(ws + o); o += 64*4;      // 27 f32x2 pairs (padded)
    float* wp2 = (float*)(ws + o); o += 896*4;     // 432 f32x2 pairs (padded)

    hipMemsetAsync(g0h, 0, (size_t)64*7*512*2*2, stream);

    wsplit_k<<<dim3(18, NR), 256, 0, stream>>>(h1w, h2w, h3w, h4w,
        w1h, w1l, w2h, w2l, w3h, w3l, w4h, w4l, c1w, c2w, wp1, wp2);

    conv12_k<<<NB*4, 256, 0, stream>>>(x, wp1, c1b, wp2, c2b, t2);
    conv3_k<<<NB, 256, 0, stream>>>(t2, c3w, c3b, t3);

    gemm_k<false><<<dim3(7, 8), 256, 0, stream>>>(
        t3, 200, fc1w, fc1b, f1, 400, NB, 400, 200, nullptr, nullptr);
    gemm_k<true><<<dim3(4, 8), 256, 0, stream>>>(
        f1, 400, fc2w, fc2b, nullptr, 0, NB, 200, 400, g0h, g0l);

    head_k<<<832, 256, 0, stream>>>(
        g0h, g0l, w1h, w1l, w2h, w2l, w3h, w3l, w4h, w4l,
        h1b, h2b, h3b, h4b, out);

    (void)in_sizes; (void)n_in; (void)out_size; (void)ws_size;
}

// Round 11
// 195.087 us; speedup vs baseline: 1.1871x; 1.0069x over previous
//
#include <hip/hip_runtime.h>

#define NB 1024
#define NR 100

typedef _Float16 half_t;
typedef half_t f16x8 __attribute__((ext_vector_type(8)));
typedef float f32x4 __attribute__((ext_vector_type(4)));
typedef float f32x2 __attribute__((ext_vector_type(2)));

__device__ __forceinline__ int kmap2(int g, int j) {
    return g*4 + (j & 3) + ((j >> 2) << 4);
}

// packed f32 fma: c += a * splat(s)  — elementwise builtin -> v_pk_fma_f32
__device__ __forceinline__ f32x2 pkfma(f32x2 a, float s, f32x2 c) {
    return __builtin_elementwise_fma(a, (f32x2){s, s}, c);
}

// async global->LDS, 16B per lane; LDS dest = base + lane*16 (HW behavior)
#define GLDS(gsrc, ldst) \
    __builtin_amdgcn_global_load_lds( \
        (const __attribute__((address_space(1))) void*)(gsrc), \
        (__attribute__((address_space(3))) void*)(ldst), 16, 0, 0)

// ---------------------------------------------------------------------------
// conv12 v2: fused conv1 -> conv2 per image quadrant (4096 blocks).
// conv1 pooled output stored in PARITY-SPLIT planes (even/odd pooled cols):
// conv2's stride-2 window reads become stride-1 across lanes -> conflict-free.
// even plane [ic][27][14] stride 14; odd plane [ic][27][13] stride 13.
// ---------------------------------------------------------------------------
#define EOFF 2268                       // 6*27*14
__global__ __launch_bounds__(256, 5) void conv12_k(const float* __restrict__ x,
        const float* __restrict__ wp1, const float* __restrict__ b1c,
        const float* __restrict__ wp2, const float* __restrict__ b2c,
        float* __restrict__ out) {
    __shared__ float img[56*56];        // 12.54 KB raw input window
    __shared__ float c1p[4374];         // 17.5 KB parity-split conv1 output
    const int blk = blockIdx.x;
    const int b  = blk >> 2;
    const int qy = (blk >> 1) & 1, qx = blk & 1;
    const int R0 = 44*qy - 1, C0 = 44*qx - 1;   // staged-window origin in x
    const int tid = threadIdx.x;
    const float* xb = x + (size_t)b * 9604;

    for (int i = tid; i < 56*56; i += 256) {
        const int rr = i / 56, cc = i - rr*56;
        const int gr = R0 + rr, gc = C0 + cc;
        float v = 0.f;
        if (gr >= 0 && gr < 98 && gc >= 0 && gc < 98) v = xb[gr*98 + gc];
        img[i] = v;
    }
    __syncthreads();

    // ---- conv1: pooled (py,px) 0..26, patch img[2py..+3][2px..+3] ----
    for (int pos = tid; pos < 729; pos += 256) {
        const int py = pos / 27, px = pos - py*27;
        float p[4][4];
        const float* base = img + (2*py)*56 + 2*px;   // 8B aligned
        #pragma unroll
        for (int u = 0; u < 4; ++u) {
            *(f32x2*)&p[u][0] = *(const f32x2*)(base + u*56);
            *(f32x2*)&p[u][2] = *(const f32x2*)(base + u*56 + 2);
        }
        f32x2 a2[3][4];
        #pragma unroll
        for (int g = 0; g < 3; ++g) {
            const f32x2 bv = *(const f32x2*)(b1c + g*2);
            a2[g][0] = a2[g][1] = a2[g][2] = a2[g][3] = bv;
        }
        #pragma unroll
        for (int ky = 0; ky < 3; ++ky)
            #pragma unroll
            for (int kx = 0; kx < 3; ++kx) {
                const int k = ky*3 + kx;
                const float q0 = p[ky  ][kx], q1 = p[ky  ][kx+1];
                const float q2 = p[ky+1][kx], q3 = p[ky+1][kx+1];
                #pragma unroll
                for (int g = 0; g < 3; ++g) {
                    const f32x2 wv = *(const f32x2*)(wp1 + (k*3+g)*2);
                    a2[g][0] = pkfma(wv, q0, a2[g][0]);
                    a2[g][1] = pkfma(wv, q1, a2[g][1]);
                    a2[g][2] = pkfma(wv, q2, a2[g][2]);
                    a2[g][3] = pkfma(wv, q3, a2[g][3]);
                }
            }
        const int par = px & 1, pi = px >> 1;
        #pragma unroll
        for (int g = 0; g < 3; ++g) {
            const float m0 = fmaxf(fmaxf(a2[g][0].x, a2[g][1].x),
                                   fmaxf(a2[g][2].x, a2[g][3].x));
            const float m1 = fmaxf(fmaxf(a2[g][0].y, a2[g][1].y),
                                   fmaxf(a2[g][2].y, a2[g][3].y));
            const int e0 = par ? (EOFF + ((2*g    )*27 + py)*13 + pi)
                               : (((2*g    )*27 + py)*14 + pi);
            const int e1 = par ? (EOFF + ((2*g + 1)*27 + py)*13 + pi)
                               : (((2*g + 1)*27 + py)*14 + pi);
            c1p[e0] = fmaxf(m0, 0.f);
            c1p[e1] = fmaxf(m1, 0.f);
        }
    }
    __syncthreads();

    // ---- conv2: reads parity planes, stride-1 across lanes ----
    const int wv_ = tid >> 6;
    const int ocg = __builtin_amdgcn_readfirstlane(tid >> 7);  // wave-uniform
    const int unit = ((wv_ & 1) << 6) | (tid & 63);            // 0..127
    if (unit >= 121) return;
    const int py = unit / 11, px = unit - py*11;
    const int y0 = 2*py;

    const float* wg = wp2 + (size_t)ocg * 432;    // 216 f32x2 pairs (scalar)
    f32x2 acc2[2][2];
    {
        const f32x2 bv = *(const f32x2*)(b2c + ocg*2);
        acc2[0][0] = acc2[0][1] = acc2[1][0] = acc2[1][1] = bv;
    }

    #pragma unroll
    for (int ic = 0; ic < 6; ++ic) {
        const float* pe0 = c1p + (ic*27 + y0)*14 + px;          // even plane
        const float* po0 = c1p + EOFF + (ic*27 + y0)*13 + px;   // odd plane
        #pragma unroll
        for (int u = 0; u < 7; ++u) {
            const float* pe = pe0 + u*14;
            const float* po = po0 + u*13;
            float pr[7];
            pr[0] = pe[0]; pr[2] = pe[1]; pr[4] = pe[2]; pr[6] = pe[3];
            pr[1] = po[0]; pr[3] = po[1]; pr[5] = po[2];
            #pragma unroll
            for (int dy = 0; dy < 2; ++dy) {
                const int ky = u - dy;
                if (ky < 0 || ky > 5) continue;
                #pragma unroll
                for (int kx = 0; kx < 6; ++kx) {
                    const f32x2 wv =
                        *(const f32x2*)(wg + (ic*36 + ky*6 + kx)*2);
                    acc2[dy][0] = pkfma(wv, pr[0+kx], acc2[dy][0]);
                    acc2[dy][1] = pkfma(wv, pr[1+kx], acc2[dy][1]);
                }
            }
        }
    }

    const int PY = qy*11 + py, PX = qx*11 + px;
    {
        const float m0 = fmaxf(fmaxf(acc2[0][0].x, acc2[0][1].x),
                               fmaxf(acc2[1][0].x, acc2[1][1].x));
        const float m1 = fmaxf(fmaxf(acc2[0][0].y, acc2[0][1].y),
                               fmaxf(acc2[1][0].y, acc2[1][1].y));
        out[(((size_t)b*4 + ocg*2    )*22 + PY)*22 + PX] = fmaxf(m0, 0.f);
        out[(((size_t)b*4 + ocg*2 + 1)*22 + PY)*22 + PX] = fmaxf(m1, 0.f);
    }
}

// ---------------------------------------------------------------------------
// conv3: in[B,4,22,22] -> out[B,200]
// ---------------------------------------------------------------------------
__global__ __launch_bounds__(256) void conv3_k(const float* __restrict__ in,
        const float* __restrict__ w, const float* __restrict__ bias,
        float* __restrict__ out) {
    __shared__ float sm[1936];
    const int b = blockIdx.x;
    const int tid = threadIdx.x;
    const float* src = in + (size_t)b * 1936;
    for (int i = tid; i < 484; i += 256)
        ((float4*)sm)[i] = ((const float4*)src)[i];
    __syncthreads();
    if (tid < 200) {
        const int c = tid / 100;
        const int rem = tid % 100;
        const int py = rem / 10, px = rem % 10;
        const int y0 = 2*py, x0 = 2*px;
        float a0, a1, a2, a3;
        a0 = a1 = a2 = a3 = bias[c];
        #pragma unroll
        for (int ic = 0; ic < 4; ++ic) {
            float p[4][4];
            const float* base = sm + ic*484 + y0*22 + x0;
            #pragma unroll
            for (int u = 0; u < 4; ++u)
                #pragma unroll
                for (int v = 0; v < 4; ++v)
                    p[u][v] = base[u*22 + v];
            #pragma unroll
            for (int ky = 0; ky < 3; ++ky) {
                #pragma unroll
                for (int kx = 0; kx < 3; ++kx) {
                    const float wv = w[(c*4 + ic)*9 + ky*3 + kx];
                    a0 = fmaf(wv, p[ky  ][kx  ], a0);
                    a1 = fmaf(wv, p[ky  ][kx+1], a1);
                    a2 = fmaf(wv, p[ky+1][kx  ], a2);
                    a3 = fmaf(wv, p[ky+1][kx+1], a3);
                }
            }
        }
        float m = fmaxf(fmaxf(a0, a1), fmaxf(a2, a3));
        out[(size_t)b*200 + tid] = fmaxf(m, 0.f);
    }
}

// ---------------------------------------------------------------------------
// f32 GEMM (fc1 / fc2), 128x64 tile. G0OUT: write packed f16 hi/lo fragment
// planes (B-fragment layout for the head kernel) instead of f32 C.
// ---------------------------------------------------------------------------
template<bool G0OUT>
__global__ __launch_bounds__(256, 4) void gemm_k(
        const float* __restrict__ A, int lda,
        const float* __restrict__ W, const float* __restrict__ bias,
        float* __restrict__ C, int ldc,
        int M, int N, int K,
        half_t* __restrict__ g0h, half_t* __restrict__ g0l) {
    __shared__ float As[32][132];
    __shared__ float Ws[32][64];
    const int m0 = blockIdx.y * 128;
    const int n0 = blockIdx.x * 64;
    const int tid = threadIdx.x;
    const int ti = tid >> 4, tj = tid & 15;
    float acc[8][4];
    #pragma unroll
    for (int i = 0; i < 8; ++i)
        #pragma unroll
        for (int j = 0; j < 4; ++j) acc[i][j] = 0.f;

    for (int k0 = 0; k0 < K; k0 += 32) {
        #pragma unroll
        for (int i = 0; i < 4; ++i) {
            const int f = tid + i*256;
            const int m = f >> 3, kg = f & 7;
            const int kk = kg*4;
            float4 v = make_float4(0.f, 0.f, 0.f, 0.f);
            if (k0 + kk < K)
                v = *(const float4*)(A + (long)(m0 + m)*lda + k0 + kk);
            As[kk+0][m] = v.x;
            As[kk+1][m] = v.y;
            As[kk+2][m] = v.z;
            As[kk+3][m] = v.w;
        }
        #pragma unroll
        for (int i = 0; i < 2; ++i) {
            const int f = tid + i*256;
            const int kk = f >> 4, cg = f & 15;
            const int n = n0 + cg*4;
            float4 v = make_float4(0.f, 0.f, 0.f, 0.f);
            if (k0 + kk < K) {
                const float* wp = W + (long)(k0 + kk)*N;
                if (n + 3 < N) v = *(const float4*)(wp + n);
                else {
                    if (n+0 < N) v.x = wp[n+0];
                    if (n+1 < N) v.y = wp[n+1];
                    if (n+2 < N) v.z = wp[n+2];
                }
            }
            *(float4*)&Ws[kk][cg*4] = v;
        }
        __syncthreads();
        #pragma unroll
        for (int kk = 0; kk < 32; ++kk) {
            float a[8], wv[4];
            *(float4*)&a[0] = *(const float4*)&As[kk][ti*8];
            *(float4*)&a[4] = *(const float4*)&As[kk][ti*8 + 4];
            *(float4*)&wv[0] = *(const float4*)&Ws[kk][tj*4];
            #pragma unroll
            for (int i = 0; i < 8; ++i)
                #pragma unroll
                for (int j = 0; j < 4; ++j)
                    acc[i][j] = fmaf(a[i], wv[j], acc[i][j]);
        }
        __syncthreads();
    }

    const int nb = n0 + tj*4;
    float bv[4] = {0.f, 0.f, 0.f, 0.f};
    #pragma unroll
    for (int e = 0; e < 4; ++e) if (nb + e < N) bv[e] = bias[nb + e];

    if (!G0OUT) {
        #pragma unroll
        for (int i = 0; i < 8; ++i) {
            const long m = m0 + ti*8 + i;
            if (nb + 3 < N) {
                float4 v;
                v.x = fmaxf(acc[i][0] + bv[0], 0.f);
                v.y = fmaxf(acc[i][1] + bv[1], 0.f);
                v.z = fmaxf(acc[i][2] + bv[2], 0.f);
                v.w = fmaxf(acc[i][3] + bv[3], 0.f);
                *(float4*)(C + m*(long)ldc + nb) = v;
            } else {
                #pragma unroll
                for (int j = 0; j < 4; ++j)
                    if (nb + j < N)
                        C[m*(long)ldc + nb + j] = fmaxf(acc[i][j] + bv[j], 0.f);
            }
        }
    } else {
        #pragma unroll
        for (int i = 0; i < 8; ++i) {
            const int m = m0 + ti*8 + i;
            #pragma unroll
            for (int j = 0; j < 4; ++j) {
                const int k = nb + j;
                if (k < N) {
                    const float v = fmaxf(acc[i][j] + bv[j], 0.f);
                    const half_t hi = (half_t)v;
                    const half_t lo = (half_t)(v - (float)hi);
                    const int kc = k >> 5, klo = k & 31;
                    const int h = klo >> 4, rm = klo & 15;
                    const int gg = rm >> 2, rr = rm & 3;
                    const size_t idx =
                        ((size_t)((m >> 4)*7 + kc)*64 + (gg << 4) + (m & 15))*8
                        + h*4 + rr;
                    g0h[idx] = hi;
                    g0l[idx] = lo;
                }
            }
        }
    }
}

// ---------------------------------------------------------------------------
// wsplit (+wpack merged at cx==17): head weights -> f16 hi/lo fragment
// planes; conv weights -> oc-pair packed arrays.
// ---------------------------------------------------------------------------
__global__ __launch_bounds__(256) void wsplit_k(
        const float* __restrict__ w1, const float* __restrict__ w2,
        const float* __restrict__ w3, const float* __restrict__ w4,
        half_t* __restrict__ f1h, half_t* __restrict__ f1l,
        half_t* __restrict__ f2h, half_t* __restrict__ f2l,
        half_t* __restrict__ f3h, half_t* __restrict__ f3l,
        half_t* __restrict__ f4h, half_t* __restrict__ f4l,
        const float* __restrict__ c1w, const float* __restrict__ c2w,
        float* __restrict__ wp1, float* __restrict__ wp2) {
    __shared__ float lds[32*140];
    const int cx = blockIdx.x, r = blockIdx.y, tid = threadIdx.x;
    if (cx == 17) {                       // wpack (one block total)
        if (r != 0) return;
        if (tid < 27) {
            const int k = tid / 3, g = tid - (tid/3)*3;
            wp1[tid*2+0] = c1w[(g*2+0)*9 + k];
            wp1[tid*2+1] = c1w[(g*2+1)*9 + k];
        }
        for (int i = tid; i < 432; i += 256) {
            const int ocg = i / 216, k = i - ocg*216;
            wp2[i*2+0] = c2w[(ocg*2+0)*216 + k];
            wp2[i*2+1] = c2w[(ocg*2+1)*216 + k];
        }
        return;
    }
    int K, N, KC, NF, kc;
    const float* src;
    half_t *dh, *dl;
    if (cx < 7)       { K=200; N=140; KC=7; NF=9; kc=cx;    src=w1; dh=f1h; dl=f1l; }
    else if (cx < 12) { K=140; N=84;  KC=5; NF=6; kc=cx-7;  src=w2; dh=f2h; dl=f2l; }
    else if (cx < 15) { K=84;  N=42;  KC=3; NF=3; kc=cx-12; src=w3; dh=f3h; dl=f3l; }
    else              { K=42;  N=4;   KC=2; NF=1; kc=cx-15; src=w4; dh=f4h; dl=f4l; }
    const float* sb = src + (size_t)r * K * N;
    for (int i = tid; i < 32*N; i += 256) {
        const int kk = i / N, n = i - kk*N;
        const int kg = kc*32 + kk;
        lds[kk*N + n] = (kg < K) ? sb[(size_t)kg*N + n] : 0.f;
    }
    __syncthreads();
    const size_t base = ((size_t)r*KC + kc)*NF*512;
    for (int e = tid; e < NF*512; e += 256) {
        const int nf = e >> 9, rem = e & 511;
        const int l = rem >> 3, j = rem & 7;
        const int g = l >> 4, c = l & 15;
        const int kl = kmap2(g, j);
        const int n = nf*16 + c;
        const float v = (n < N) ? lds[kl*N + n] : 0.f;
        const half_t hi = (half_t)v;
        const half_t lo = (half_t)(v - (float)hi);
        dh[base + (size_t)nf*512 + rem] = hi;
        dl[base + (size_t)nf*512 + rem] = lo;
    }
}

// ---------------------------------------------------------------------------
// head_k v3: fused chain, split-f16 MFMA, single-barrier double-buffered
// LDS weight staging (36 KB ping-pong) + cross-layer prefetch.
// ---------------------------------------------------------------------------
#define MFMA(a, b, c) __builtin_amdgcn_mfma_f32_16x16x32_f16(a, b, c, 0, 0, 0)

__global__ __launch_bounds__(256, 2) void head_k(
        const half_t* __restrict__ g0h, const half_t* __restrict__ g0l,
        const half_t* __restrict__ w1h, const half_t* __restrict__ w1l,
        const half_t* __restrict__ w2h, const half_t* __restrict__ w2l,
        const half_t* __restrict__ w3h, const half_t* __restrict__ w3l,
        const half_t* __restrict__ w4h, const half_t* __restrict__ w4l,
        const float* __restrict__ b1, const float* __restrict__ b2,
        const float* __restrict__ b3, const float* __restrict__ b4,
        float* __restrict__ out) {
    constexpr int CH = 18*512;          // one L1 chunk (9 hi + 9 lo planes)
    __shared__ half_t wb[2*CH];         // 36 KB double buffer
    __shared__ float bl[270];
    const int bid = blockIdx.x;
    const int cx  = bid & 7;
    const int kb  = bid >> 3;
    const int r   = ((kb >> 3) << 3) + cx;
    if (r >= NR) return;
    const int mt  = kb & 7;
    const int tid = threadIdx.x;
    if (tid < 140) bl[tid]       = b1[(size_t)r*140 + tid];
    if (tid < 84)  bl[140 + tid] = b2[(size_t)r*84  + tid];
    if (tid < 42)  bl[224 + tid] = b3[(size_t)r*42  + tid];
    if (tid < 4)   bl[266 + tid] = b4[(size_t)r*4   + tid];
    const int w = tid >> 6, l = tid & 63;
    const int g4 = ((l >> 4) & 3) * 4;
    const int mb0 = mt*8 + w*2;
    const size_t loff = (size_t)l * 8;

    auto stage1 = [&](int kc, half_t* buf) {
        const half_t* hs = w1h + ((size_t)r*7 + kc)*9*512;
        const half_t* ls = w1l + ((size_t)r*7 + kc)*9*512;
        #pragma unroll
        for (int p0 = 0; p0 < 3; ++p0) {
            const int p = w + p0*4;
            if (p < 9) {
                GLDS(hs + (size_t)p*512 + loff, buf + p*512);
                GLDS(ls + (size_t)p*512 + loff, buf + (9+p)*512);
            }
        }
    };
    auto stage2 = [&](int kc, half_t* buf) {
        const half_t* hs = w2h + ((size_t)r*5 + kc)*6*512;
        const half_t* ls = w2l + ((size_t)r*5 + kc)*6*512;
        #pragma unroll
        for (int p0 = 0; p0 < 2; ++p0) {
            const int p = w + p0*4;
            if (p < 6) {
                GLDS(hs + (size_t)p*512 + loff, buf + p*512);
                GLDS(ls + (size_t)p*512 + loff, buf + (6+p)*512);
            }
        }
    };
    auto stage3 = [&](int kc, half_t* buf) {
        const half_t* hs = w3h + ((size_t)r*3 + kc)*3*512;
        const half_t* ls = w3l + ((size_t)r*3 + kc)*3*512;
        if (w < 3) {
            GLDS(hs + (size_t)w*512 + loff, buf + w*512);
            GLDS(ls + (size_t)w*512 + loff, buf + (3+w)*512);
        }
    };

    // ===================== L1: K=200 (7 chunks), N=140 (9 frags) ==========
    f16x8 bhv[2][2], blv[2][2];         // [buf parity][mb]
    stage1(0, wb);
    #pragma unroll
    for (int mb = 0; mb < 2; ++mb) {
        const size_t bo = ((size_t)(mb0 + mb)*7 + 0)*512 + loff;
        bhv[0][mb] = *(const f16x8*)(g0h + bo);
        blv[0][mb] = *(const f16x8*)(g0l + bo);
    }
    __syncthreads();
    f32x4 a1[2][9] = {};
    #pragma unroll
    for (int kc = 0; kc < 7; ++kc) {
        const half_t* cur = wb + (kc & 1)*CH;
        if (kc < 6) {
            stage1(kc+1, wb + ((kc+1) & 1)*CH);
            #pragma unroll
            for (int mb = 0; mb < 2; ++mb) {
                const size_t bo = ((size_t)(mb0 + mb)*7 + kc + 1)*512 + loff;
                bhv[(kc+1)&1][mb] = *(const f16x8*)(g0h + bo);
                blv[(kc+1)&1][mb] = *(const f16x8*)(g0l + bo);
            }
        } else {
            stage2(0, wb + CH);   // kc=6 reads buf0 -> prefetch L2 kc0 to buf1
        }
        #pragma unroll
        for (int nf = 0; nf < 9; ++nf) {
            const f16x8 wh = *(const f16x8*)(cur + nf*512 + loff);
            const f16x8 wl = *(const f16x8*)(cur + (9+nf)*512 + loff);
            #pragma unroll
            for (int mb = 0; mb < 2; ++mb) {
                a1[mb][nf] = MFMA(wh, bhv[kc&1][mb], a1[mb][nf]);
                a1[mb][nf] = MFMA(wh, blv[kc&1][mb], a1[mb][nf]);
                a1[mb][nf] = MFMA(wl, bhv[kc&1][mb], a1[mb][nf]);
            }
        }
        __syncthreads();
    }
    // ---- convert a1 -> L2 B-fragments (bias+relu+split), N1=140 ----
    f16x8 b2h[2][5], b2l[2][5];
    #pragma unroll
    for (int kc = 0; kc < 5; ++kc)
        #pragma unroll
        for (int h = 0; h < 2; ++h) {
            const int nf = kc*2 + h;
            #pragma unroll
            for (int mb = 0; mb < 2; ++mb)
                #pragma unroll
                for (int rr = 0; rr < 4; ++rr) {
                    float v = 0.f;
                    if (nf < 9) {
                        const int n = nf*16 + g4 + rr;
                        v = (n < 140) ? fmaxf(a1[mb][nf][rr] + bl[n], 0.f) : 0.f;
                    }
                    const half_t hi = (half_t)v;
                    const half_t lo = (half_t)(v - (float)hi);
                    b2h[mb][kc][h*4+rr] = hi;
                    b2l[mb][kc][h*4+rr] = lo;
                }
        }
    // ===================== L2: K=140 (5 chunks), N=84 (6 frags) ===========
    f32x4 a2[2][6] = {};
    #pragma unroll
    for (int kc = 0; kc < 5; ++kc) {
        const half_t* cur = wb + (((kc+1) & 1))*CH;
        if (kc < 4) stage2(kc+1, wb + (kc & 1)*CH);
        else        stage3(0,    wb + (kc & 1)*CH);
        #pragma unroll
        for (int nf = 0; nf < 6; ++nf) {
            const f16x8 wh = *(const f16x8*)(cur + nf*512 + loff);
            const f16x8 wl = *(const f16x8*)(cur + (6+nf)*512 + loff);
            #pragma unroll
            for (int mb = 0; mb < 2; ++mb) {
                a2[mb][nf] = MFMA(wh, b2h[mb][kc], a2[mb][nf]);
                a2[mb][nf] = MFMA(wh, b2l[mb][kc], a2[mb][nf]);
                a2[mb][nf] = MFMA(wl, b2h[mb][kc], a2[mb][nf]);
            }
        }
        __syncthreads();
    }
    // ---- convert a2 -> L3 B-fragments, N2=84 ----
    f16x8 b3h[2][3], b3l[2][3];
    #pragma unroll
    for (int kc = 0; kc < 3; ++kc)
        #pragma unroll
        for (int h = 0; h < 2; ++h) {
            const int nf = kc*2 + h;
            #pragma unroll
            for (int mb = 0; mb < 2; ++mb)
                #pragma unroll
                for (int rr = 0; rr < 4; ++rr) {
                    float v = 0.f;
                    if (nf < 6) {
                        const int n = nf*16 + g4 + rr;
                        v = (n < 84) ? fmaxf(a2[mb][nf][rr] + bl[140 + n], 0.f) : 0.f;
                    }
                    const half_t hi = (half_t)v;
                    const half_t lo = (half_t)(v - (float)hi);
                    b3h[mb][kc][h*4+rr] = hi;
                    b3l[mb][kc][h*4+rr] = lo;
                }
        }
    // ===================== L3: K=84 (3 chunks), N=42 (3 frags) ============
    f32x4 a3[2][3] = {};
    #pragma unroll
    for (int kc = 0; kc < 3; ++kc) {
        const half_t* cur = wb + (kc & 1)*CH;
        if (kc < 2) stage3(kc+1, wb + ((kc+1) & 1)*CH);
        #pragma unroll
        for (int nf = 0; nf < 3; ++nf) {
            const f16x8 wh = *(const f16x8*)(cur + nf*512 + loff);
            const f16x8 wl = *(const f16x8*)(cur + (3+nf)*512 + loff);
            #pragma unroll
            for (int mb = 0; mb < 2; ++mb) {
                a3[mb][nf] = MFMA(wh, b3h[mb][kc], a3[mb][nf]);
                a3[mb][nf] = MFMA(wh, b3l[mb][kc], a3[mb][nf]);
                a3[mb][nf] = MFMA(wl, b3h[mb][kc], a3[mb][nf]);
            }
        }
        __syncthreads();
    }
    // ---- convert a3 -> L4 B-fragments, N3=42 ----
    f16x8 b4h[2][2], b4l[2][2];
    #pragma unroll
    for (int kc = 0; kc < 2; ++kc)
        #pragma unroll
        for (int h = 0; h < 2; ++h) {
            const int nf = kc*2 + h;
            #pragma unroll
            for (int mb = 0; mb < 2; ++mb)
                #pragma unroll
                for (int rr = 0; rr < 4; ++rr) {
                    float v = 0.f;
                    if (nf < 3) {
                        const int n = nf*16 + g4 + rr;
                        v = (n < 42) ? fmaxf(a3[mb][nf][rr] + bl[224 + n], 0.f) : 0.f;
                    }
                    const half_t hi = (half_t)v;
                    const half_t lo = (half_t)(v - (float)hi);
                    b4h[mb][kc][h*4+rr] = hi;
                    b4l[mb][kc][h*4+rr] = lo;
                }
        }
    // ===================== L4: K=42 (2 chunks), N=4 — direct global =======
    f32x4 a4[2] = {};
    #pragma unroll
    for (int kc = 0; kc < 2; ++kc) {
        const size_t wo = ((size_t)r*2 + kc)*512 + loff;
        const f16x8 wh = *(const f16x8*)(w4h + wo);
        const f16x8 wl = *(const f16x8*)(w4l + wo);
        #pragma unroll
        for (int mb = 0; mb < 2; ++mb) {
            a4[mb] = MFMA(wh, b4h[mb][kc], a4[mb]);
            a4[mb] = MFMA(wh, b4l[mb][kc], a4[mb]);
            a4[mb] = MFMA(wl, b4h[mb][kc], a4[mb]);
        }
    }
    if ((l >> 4) == 0) {
        #pragma unroll
        for (int mb = 0; mb < 2; ++mb) {
            const int b = (mb0 + mb)*16 + (l & 15);
            float4 o;
            o.x = a4[mb][0] + bl[266];
            o.y = a4[mb][1] + bl[267];
            o.z = a4[mb][2] + bl[268];
            o.w = a4[mb][3] + bl[269];
            *(float4*)(out + (size_t)b*400 + r*4) = o;
        }
    }
}

extern "C" void kernel_launch(void* const* d_in, const int* in_sizes, int n_in,
                              void* d_out, int out_size, void* d_ws, size_t ws_size,
                              hipStream_t stream) {
    const float* x    = (const float*)d_in[0];
    const float* c1w  = (const float*)d_in[1];
    const float* c1b  = (const float*)d_in[2];
    const float* c2w  = (const float*)d_in[3];
    const float* c2b  = (const float*)d_in[4];
    const float* c3w  = (const float*)d_in[5];
    const float* c3b  = (const float*)d_in[6];
    const float* fc1w = (const float*)d_in[7];
    const float* fc1b = (const float*)d_in[8];
    const float* fc2w = (const float*)d_in[9];
    const float* fc2b = (const float*)d_in[10];
    const float* h1w  = (const float*)d_in[11];
    const float* h1b  = (const float*)d_in[12];
    const float* h2w  = (const float*)d_in[13];
    const float* h2b  = (const float*)d_in[14];
    const float* h3w  = (const float*)d_in[15];
    const float* h3b  = (const float*)d_in[16];
    const float* h4w  = (const float*)d_in[17];
    const float* h4b  = (const float*)d_in[18];
    float* out = (float*)d_out;

    char* ws = (char*)d_ws;
    size_t o = 0;
    float* t2 = (float*)(ws + o); o += (size_t)NB*4*484*4;
    float* t3 = (float*)(ws + o); o += (size_t)NB*200*4;
    float* f1 = (float*)(ws + o); o += (size_t)NB*400*4;
    half_t* g0h = (half_t*)(ws + o); o += (size_t)64*7*512*2;
    half_t* g0l = (half_t*)(ws + o); o += (size_t)64*7*512*2;
    half_t* w1h = (half_t*)(ws + o); o += (size_t)NR*7*9*512*2;
    half_t* w1l = (half_t*)(ws + o); o += (size_t)NR*7*9*512*2;
    half_t* w2h = (half_t*)(ws + o); o += (size_t)NR*5*6*512*2;
    half_t* w2l = (half_t*)(ws + o); o += (size_t)NR*5*6*512*2;
    half_t* w3h = (half_t*)(ws + o); o += (size_t)NR*3*3*512*2;
    half_t* w3l = (half_t*)(ws + o); o += (size_t)NR*3*3*512*2;
    half_t* w4h = (half_t*)(ws + o); o += (size_t)NR*2*1*512*2;
    half_t* w4l = (half_t*)(ws + o); o += (size_t)NR*2*1*512*2;
    float* wp1 = (float*)(ws + o); o += 64*4;      // 27 f32x2 pairs (padded)
    float* wp2 = (float*)(ws + o); o += 896*4;     // 432 f32x2 pairs (padded)

    hipMemsetAsync(g0h, 0, (size_t)64*7*512*2*2, stream);

    wsplit_k<<<dim3(18, NR), 256, 0, stream>>>(h1w, h2w, h3w, h4w,
        w1h, w1l, w2h, w2l, w3h, w3l, w4h, w4l, c1w, c2w, wp1, wp2);

    conv12_k<<<NB*4, 256, 0, stream>>>(x, wp1, c1b, wp2, c2b, t2);
    conv3_k<<<NB, 256, 0, stream>>>(t2, c3w, c3b, t3);

    gemm_k<false><<<dim3(7, 8), 256, 0, stream>>>(
        t3, 200, fc1w, fc1b, f1, 400, NB, 400, 200, nullptr, nullptr);
    gemm_k<true><<<dim3(4, 8), 256, 0, stream>>>(
        f1, 400, fc2w, fc2b, nullptr, 0, NB, 200, 400, g0h, g0l);

    head_k<<<832, 256, 0, stream>>>(
        g0h, g0l, w1h, w1l, w2h, w2l, w3h, w3l, w4h, w4l,
        h1b, h2b, h3b, h4b, out);

    (void)in_sizes; (void)n_in; (void)out_size; (void)ws_size;
}

// Round 12
// 184.309 us; speedup vs baseline: 1.2565x; 1.0585x over previous
//
#include <hip/hip_runtime.h>

#define NB 1024
#define NR 100

typedef _Float16 half_t;
typedef half_t f16x8 __attribute__((ext_vector_type(8)));
typedef float f32x4 __attribute__((ext_vector_type(4)));
typedef float f32x2 __attribute__((ext_vector_type(2)));

__device__ __forceinline__ int kmap2(int g, int j) {
    return g*4 + (j & 3) + ((j >> 2) << 4);
}

// packed f32 fma: c += a * splat(s)  -> v_pk_fma_f32
__device__ __forceinline__ f32x2 pkfma(f32x2 a, float s, f32x2 c) {
    return __builtin_elementwise_fma(a, (f32x2){s, s}, c);
}

// async global->LDS, 16B per lane; LDS dest = base + lane*16 (HW behavior)
#define GLDS(gsrc, ldst) \
    __builtin_amdgcn_global_load_lds( \
        (const __attribute__((address_space(1))) void*)(gsrc), \
        (__attribute__((address_space(3))) void*)(ldst), 16, 0, 0)

// ---------------------------------------------------------------------------
// wpack: conv weights -> oc-pair-packed f32x2 arrays (1 block).
// ---------------------------------------------------------------------------
__global__ __launch_bounds__(256) void wpack_k(
        const float* __restrict__ c1w, const float* __restrict__ c2w,
        float* __restrict__ wp1, float* __restrict__ wp2) {
    const int t = threadIdx.x;
    if (t < 27) {
        const int k = t / 3, g = t - (t/3)*3;
        wp1[t*2+0] = c1w[(g*2+0)*9 + k];
        wp1[t*2+1] = c1w[(g*2+1)*9 + k];
    }
    for (int i = t; i < 432; i += 256) {
        const int ocg = i / 216, k = i - ocg*216;
        wp2[i*2+0] = c2w[(ocg*2+0)*216 + k];
        wp2[i*2+1] = c2w[(ocg*2+1)*216 + k];
    }
}

// ---------------------------------------------------------------------------
// conv12 v3: fused conv1 -> conv2 per image quadrant (4096 blocks).
// img staged PARITY-SPLIT (conv1 stride-2 reads -> stride-1, conflict-free).
// conv1 output c1p parity-split (as v2). conv2 IC-SPLIT: waves 0-1 do ic 0-2,
// waves 2-3 do ic 3-5, each active lane computes ALL 4 oc for its cell
// (half the LDS reads); partials exchanged via dead img buffer.
// ---------------------------------------------------------------------------
#define EOFF 2268                       // 6*27*14 (even-plane size of c1p)
#define IO   1568                       // 56*28  (odd img plane offset)
__global__ __launch_bounds__(256, 5) void conv12_k(const float* __restrict__ x,
        const float* __restrict__ wp1, const float* __restrict__ b1c,
        const float* __restrict__ wp2, const float* __restrict__ b2c,
        float* __restrict__ out) {
    __shared__ float img[3136];         // 12.54 KB (even|odd planes 56x28)
    __shared__ float c1p[4374];         // 17.5 KB parity-split conv1 output
    const int blk = blockIdx.x;
    const int b  = blk >> 2;
    const int qy = (blk >> 1) & 1, qx = blk & 1;
    const int R0 = 44*qy - 1, C0 = 44*qx - 1;
    const int tid = threadIdx.x;
    const float* xb = x + (size_t)b * 9604;

    for (int i = tid; i < 3136; i += 256) {
        const int rr = i / 56, cc = i - rr*56;
        const int gr = R0 + rr, gc = C0 + cc;
        float v = 0.f;
        if (gr >= 0 && gr < 98 && gc >= 0 && gc < 98) v = xb[gr*98 + gc];
        img[((cc & 1) ? IO : 0) + rr*28 + (cc >> 1)] = v;
    }
    __syncthreads();

    // ---- conv1: pooled (py,px) 0..26; cols 2px..2px+3 -> e{px,px+1}, o{px,px+1}
    for (int pos = tid; pos < 729; pos += 256) {
        const int py = pos / 27, px = pos - py*27;
        float p[4][4];
        #pragma unroll
        for (int u = 0; u < 4; ++u) {
            const int ro = (2*py + u)*28;
            p[u][0] = img[ro + px];
            p[u][2] = img[ro + px + 1];
            p[u][1] = img[IO + ro + px];
            p[u][3] = img[IO + ro + px + 1];
        }
        f32x2 a2[3][4];
        #pragma unroll
        for (int g = 0; g < 3; ++g) {
            const f32x2 bv = *(const f32x2*)(b1c + g*2);
            a2[g][0] = a2[g][1] = a2[g][2] = a2[g][3] = bv;
        }
        #pragma unroll
        for (int ky = 0; ky < 3; ++ky)
            #pragma unroll
            for (int kx = 0; kx < 3; ++kx) {
                const int k = ky*3 + kx;
                const float q0 = p[ky  ][kx], q1 = p[ky  ][kx+1];
                const float q2 = p[ky+1][kx], q3 = p[ky+1][kx+1];
                #pragma unroll
                for (int g = 0; g < 3; ++g) {
                    const f32x2 wv = *(const f32x2*)(wp1 + (k*3+g)*2);
                    a2[g][0] = pkfma(wv, q0, a2[g][0]);
                    a2[g][1] = pkfma(wv, q1, a2[g][1]);
                    a2[g][2] = pkfma(wv, q2, a2[g][2]);
                    a2[g][3] = pkfma(wv, q3, a2[g][3]);
                }
            }
        const int par = px & 1, pi = px >> 1;
        #pragma unroll
        for (int g = 0; g < 3; ++g) {
            const float m0 = fmaxf(fmaxf(a2[g][0].x, a2[g][1].x),
                                   fmaxf(a2[g][2].x, a2[g][3].x));
            const float m1 = fmaxf(fmaxf(a2[g][0].y, a2[g][1].y),
                                   fmaxf(a2[g][2].y, a2[g][3].y));
            const int e0 = par ? (EOFF + ((2*g    )*27 + py)*13 + pi)
                               : (((2*g    )*27 + py)*14 + pi);
            const int e1 = par ? (EOFF + ((2*g + 1)*27 + py)*13 + pi)
                               : (((2*g + 1)*27 + py)*14 + pi);
            c1p[e0] = fmaxf(m0, 0.f);
            c1p[e1] = fmaxf(m1, 0.f);
        }
    }
    __syncthreads();

    // ---- conv2: ic-split, 4 oc per active lane ----
    const int wv_ = tid >> 6;
    const int ich = __builtin_amdgcn_readfirstlane(tid >> 7);  // ic half
    const int unit = ((wv_ & 1) << 6) | (tid & 63);            // 0..127
    const bool act = unit < 121;
    const int py = act ? unit / 11 : 0;
    const int px = act ? unit - py*11 : 0;
    const int y0 = 2*py;

    f32x2 acc[2][2][2] = {};            // [oc-pair][dy][dx]
    if (act) {
        #pragma unroll
        for (int ic3 = 0; ic3 < 3; ++ic3) {
            const int ic = ich*3 + ic3;
            const float* pe0 = c1p + (ic*27 + y0)*14 + px;
            const float* po0 = c1p + EOFF + (ic*27 + y0)*13 + px;
            #pragma unroll
            for (int u = 0; u < 7; ++u) {
                const float* pe = pe0 + u*14;
                const float* po = po0 + u*13;
                float pr[7];
                pr[0] = pe[0]; pr[2] = pe[1]; pr[4] = pe[2]; pr[6] = pe[3];
                pr[1] = po[0]; pr[3] = po[1]; pr[5] = po[2];
                #pragma unroll
                for (int dy = 0; dy < 2; ++dy) {
                    const int ky = u - dy;
                    if (ky < 0 || ky > 5) continue;
                    #pragma unroll
                    for (int kx = 0; kx < 6; ++kx) {
                        const f32x2 w0 =
                            *(const f32x2*)(wp2 + (ic*36 + ky*6 + kx)*2);
                        const f32x2 w1 =
                            *(const f32x2*)(wp2 + 432 + (ic*36 + ky*6 + kx)*2);
                        acc[0][dy][0] = pkfma(w0, pr[0+kx], acc[0][dy][0]);
                        acc[0][dy][1] = pkfma(w0, pr[1+kx], acc[0][dy][1]);
                        acc[1][dy][0] = pkfma(w1, pr[0+kx], acc[1][dy][0]);
                        acc[1][dy][1] = pkfma(w1, pr[1+kx], acc[1][dy][1]);
                    }
                }
            }
        }
    }
    // exchange: ich==1 writes partials into img (dead after conv1 phase)
    float* pbuf = img;                  // [16][128] layout, conflict-free
    if (act && ich == 1) {
        #pragma unroll
        for (int p = 0; p < 2; ++p)
            #pragma unroll
            for (int dy = 0; dy < 2; ++dy)
                #pragma unroll
                for (int dx = 0; dx < 2; ++dx) {
                    const int j = ((p*2 + dy)*2 + dx)*2;
                    pbuf[(j    )*128 + unit] = acc[p][dy][dx].x;
                    pbuf[(j + 1)*128 + unit] = acc[p][dy][dx].y;
                }
    }
    __syncthreads();
    if (act && ich == 0) {
        #pragma unroll
        for (int p = 0; p < 2; ++p)
            #pragma unroll
            for (int dy = 0; dy < 2; ++dy)
                #pragma unroll
                for (int dx = 0; dx < 2; ++dx) {
                    const int j = ((p*2 + dy)*2 + dx)*2;
                    acc[p][dy][dx].x += pbuf[(j    )*128 + unit];
                    acc[p][dy][dx].y += pbuf[(j + 1)*128 + unit];
                }
        const int PY = qy*11 + py, PX = qx*11 + px;
        #pragma unroll
        for (int p = 0; p < 2; ++p) {
            const f32x2 bv = *(const f32x2*)(b2c + p*2);
            const float m0 = fmaxf(fmaxf(acc[p][0][0].x, acc[p][0][1].x),
                                   fmaxf(acc[p][1][0].x, acc[p][1][1].x)) + bv.x;
            const float m1 = fmaxf(fmaxf(acc[p][0][0].y, acc[p][0][1].y),
                                   fmaxf(acc[p][1][0].y, acc[p][1][1].y)) + bv.y;
            out[(((size_t)b*4 + p*2    )*22 + PY)*22 + PX] = fmaxf(m0, 0.f);
            out[(((size_t)b*4 + p*2 + 1)*22 + PY)*22 + PX] = fmaxf(m1, 0.f);
        }
    }
}

// ---------------------------------------------------------------------------
// conv3: in[B,4,22,22] -> out[B,200]
// ---------------------------------------------------------------------------
__global__ __launch_bounds__(256) void conv3_k(const float* __restrict__ in,
        const float* __restrict__ w, const float* __restrict__ bias,
        float* __restrict__ out) {
    __shared__ float sm[1936];
    const int b = blockIdx.x;
    const int tid = threadIdx.x;
    const float* src = in + (size_t)b * 1936;
    for (int i = tid; i < 484; i += 256)
        ((float4*)sm)[i] = ((const float4*)src)[i];
    __syncthreads();
    if (tid < 200) {
        const int c = tid / 100;
        const int rem = tid % 100;
        const int py = rem / 10, px = rem % 10;
        const int y0 = 2*py, x0 = 2*px;
        float a0, a1, a2, a3;
        a0 = a1 = a2 = a3 = bias[c];
        #pragma unroll
        for (int ic = 0; ic < 4; ++ic) {
            float p[4][4];
            const float* base = sm + ic*484 + y0*22 + x0;
            #pragma unroll
            for (int u = 0; u < 4; ++u)
                #pragma unroll
                for (int v = 0; v < 4; ++v)
                    p[u][v] = base[u*22 + v];
            #pragma unroll
            for (int ky = 0; ky < 3; ++ky) {
                #pragma unroll
                for (int kx = 0; kx < 3; ++kx) {
                    const float wv = w[(c*4 + ic)*9 + ky*3 + kx];
                    a0 = fmaf(wv, p[ky  ][kx  ], a0);
                    a1 = fmaf(wv, p[ky  ][kx+1], a1);
                    a2 = fmaf(wv, p[ky+1][kx  ], a2);
                    a3 = fmaf(wv, p[ky+1][kx+1], a3);
                }
            }
        }
        float m = fmaxf(fmaxf(a0, a1), fmaxf(a2, a3));
        out[(size_t)b*200 + tid] = fmaxf(m, 0.f);
    }
}

// ---------------------------------------------------------------------------
// gemm body (shared by fc1 kernel and the fused fc2+wsplit kernel).
// G0OUT: write packed f16 hi/lo fragment planes; also zero-fills the
// k in [N,224) pad slots (replaces the old memset).
// ---------------------------------------------------------------------------
template<bool G0OUT>
__device__ __forceinline__ void gemm_body(float* pool, int bx, int by,
        const float* __restrict__ A, int lda,
        const float* __restrict__ W, const float* __restrict__ bias,
        float* __restrict__ C, int ldc,
        int M, int N, int K,
        half_t* __restrict__ g0h, half_t* __restrict__ g0l) {
    float (*As)[132] = (float(*)[132])pool;     // 32*132
    float* Ws = pool + 32*132;                  // 32*64
    const int m0 = by * 128;
    const int n0 = bx * 64;
    const int tid = threadIdx.x;
    const int ti = tid >> 4, tj = tid & 15;
    float acc[8][4];
    #pragma unroll
    for (int i = 0; i < 8; ++i)
        #pragma unroll
        for (int j = 0; j < 4; ++j) acc[i][j] = 0.f;

    for (int k0 = 0; k0 < K; k0 += 32) {
        #pragma unroll
        for (int i = 0; i < 4; ++i) {
            const int f = tid + i*256;
            const int m = f >> 3, kg = f & 7;
            const int kk = kg*4;
            float4 v = make_float4(0.f, 0.f, 0.f, 0.f);
            if (k0 + kk < K)
                v = *(const float4*)(A + (long)(m0 + m)*lda + k0 + kk);
            As[kk+0][m] = v.x;
            As[kk+1][m] = v.y;
            As[kk+2][m] = v.z;
            As[kk+3][m] = v.w;
        }
        #pragma unroll
        for (int i = 0; i < 2; ++i) {
            const int f = tid + i*256;
            const int kk = f >> 4, cg = f & 15;
            const int n = n0 + cg*4;
            float4 v = make_float4(0.f, 0.f, 0.f, 0.f);
            if (k0 + kk < K) {
                const float* wp = W + (long)(k0 + kk)*N;
                if (n + 3 < N) v = *(const float4*)(wp + n);
                else {
                    if (n+0 < N) v.x = wp[n+0];
                    if (n+1 < N) v.y = wp[n+1];
                    if (n+2 < N) v.z = wp[n+2];
                }
            }
            *(float4*)&Ws[kk*64 + cg*4] = v;
        }
        __syncthreads();
        #pragma unroll
        for (int kk = 0; kk < 32; ++kk) {
            float a[8], wv[4];
            *(float4*)&a[0] = *(const float4*)&As[kk][ti*8];
            *(float4*)&a[4] = *(const float4*)&As[kk][ti*8 + 4];
            *(float4*)&wv[0] = *(const float4*)&Ws[kk*64 + tj*4];
            #pragma unroll
            for (int i = 0; i < 8; ++i)
                #pragma unroll
                for (int j = 0; j < 4; ++j)
                    acc[i][j] = fmaf(a[i], wv[j], acc[i][j]);
        }
        __syncthreads();
    }

    const int nb = n0 + tj*4;
    float bv[4] = {0.f, 0.f, 0.f, 0.f};
    #pragma unroll
    for (int e = 0; e < 4; ++e) if (nb + e < N) bv[e] = bias[nb + e];

    if (!G0OUT) {
        #pragma unroll
        for (int i = 0; i < 8; ++i) {
            const long m = m0 + ti*8 + i;
            if (nb + 3 < N) {
                float4 v;
                v.x = fmaxf(acc[i][0] + bv[0], 0.f);
                v.y = fmaxf(acc[i][1] + bv[1], 0.f);
                v.z = fmaxf(acc[i][2] + bv[2], 0.f);
                v.w = fmaxf(acc[i][3] + bv[3], 0.f);
                *(float4*)(C + m*(long)ldc + nb) = v;
            } else {
                #pragma unroll
                for (int j = 0; j < 4; ++j)
                    if (nb + j < N)
                        C[m*(long)ldc + nb + j] = fmaxf(acc[i][j] + bv[j], 0.f);
            }
        }
    } else {
        #pragma unroll
        for (int i = 0; i < 8; ++i) {
            const int m = m0 + ti*8 + i;
            #pragma unroll
            for (int j = 0; j < 4; ++j) {
                const int k = nb + j;
                if (k < 224) {                  // incl. zero pad [N,224)
                    float v = 0.f;
                    if (k < N) v = fmaxf(acc[i][j] + bv[j], 0.f);
                    const half_t hi = (half_t)v;
                    const half_t lo = (half_t)(v - (float)hi);
                    const int kc = k >> 5, klo = k & 31;
                    const int h = klo >> 4, rm = klo & 15;
                    const int gg = rm >> 2, rr = rm & 3;
                    const size_t idx =
                        ((size_t)((m >> 4)*7 + kc)*64 + (gg << 4) + (m & 15))*8
                        + h*4 + rr;
                    g0h[idx] = hi;
                    g0l[idx] = lo;
                }
            }
        }
    }
}

__global__ __launch_bounds__(256, 4) void fc1_k(
        const float* __restrict__ A, const float* __restrict__ W,
        const float* __restrict__ bias, float* __restrict__ C) {
    __shared__ float pool[32*132 + 32*64];
    gemm_body<false>(pool, blockIdx.x, blockIdx.y, A, 200, W, bias, C, 400,
                     NB, 400, 200, nullptr, nullptr);
}

// ---------------------------------------------------------------------------
// fc2ws: blocks 0..31 = fc2 gemm (G0OUT); blocks 32..1731 = wsplit (17 x 100).
// Independent work, disjoint outputs — legal in one launch.
// ---------------------------------------------------------------------------
__global__ __launch_bounds__(256, 4) void fc2ws_k(
        const float* __restrict__ A, const float* __restrict__ W,
        const float* __restrict__ bias,
        half_t* __restrict__ g0h, half_t* __restrict__ g0l,
        const float* __restrict__ w1, const float* __restrict__ w2,
        const float* __restrict__ w3, const float* __restrict__ w4,
        half_t* __restrict__ f1h, half_t* __restrict__ f1l,
        half_t* __restrict__ f2h, half_t* __restrict__ f2l,
        half_t* __restrict__ f3h, half_t* __restrict__ f3l,
        half_t* __restrict__ f4h, half_t* __restrict__ f4l) {
    __shared__ float pool[32*132 + 32*64];      // 24.5 KB (wsplit uses 4480)
    const int bid = blockIdx.x;
    const int tid = threadIdx.x;
    if (bid < 32) {
        gemm_body<true>(pool, bid & 3, bid >> 2, A, 400, W, bias,
                        nullptr, 0, NB, 200, 400, g0h, g0l);
        return;
    }
    // ---- wsplit part ----
    const int w = bid - 32;
    const int cx = w % 17, r = w / 17;
    float* lds = pool;
    int K, N, KC, NF, kc;
    const float* src;
    half_t *dh, *dl;
    if (cx < 7)       { K=200; N=140; KC=7; NF=9; kc=cx;    src=w1; dh=f1h; dl=f1l; }
    else if (cx < 12) { K=140; N=84;  KC=5; NF=6; kc=cx-7;  src=w2; dh=f2h; dl=f2l; }
    else if (cx < 15) { K=84;  N=42;  KC=3; NF=3; kc=cx-12; src=w3; dh=f3h; dl=f3l; }
    else              { K=42;  N=4;   KC=2; NF=1; kc=cx-15; src=w4; dh=f4h; dl=f4l; }
    const float* sb = src + (size_t)r * K * N;
    for (int i = tid; i < 32*N; i += 256) {
        const int kk = i / N, n = i - kk*N;
        const int kg = kc*32 + kk;
        lds[kk*N + n] = (kg < K) ? sb[(size_t)kg*N + n] : 0.f;
    }
    __syncthreads();
    const size_t base = ((size_t)r*KC + kc)*NF*512;
    for (int e = tid; e < NF*512; e += 256) {
        const int nf = e >> 9, rem = e & 511;
        const int l = rem >> 3, j = rem & 7;
        const int g = l >> 4, c = l & 15;
        const int kl = kmap2(g, j);
        const int n = nf*16 + c;
        const float v = (n < N) ? lds[kl*N + n] : 0.f;
        const half_t hi = (half_t)v;
        const half_t lo = (half_t)(v - (float)hi);
        dh[base + (size_t)nf*512 + rem] = hi;
        dl[base + (size_t)nf*512 + rem] = lo;
    }
}

// ---------------------------------------------------------------------------
// head_k: fused chain, split-f16 MFMA, single-barrier double-buffered
// LDS weight staging (36 KB ping-pong) + cross-layer prefetch.
// ---------------------------------------------------------------------------
#define MFMA(a, b, c) __builtin_amdgcn_mfma_f32_16x16x32_f16(a, b, c, 0, 0, 0)

__global__ __launch_bounds__(256, 2) void head_k(
        const half_t* __restrict__ g0h, const half_t* __restrict__ g0l,
        const half_t* __restrict__ w1h, const half_t* __restrict__ w1l,
        const half_t* __restrict__ w2h, const half_t* __restrict__ w2l,
        const half_t* __restrict__ w3h, const half_t* __restrict__ w3l,
        const half_t* __restrict__ w4h, const half_t* __restrict__ w4l,
        const float* __restrict__ b1, const float* __restrict__ b2,
        const float* __restrict__ b3, const float* __restrict__ b4,
        float* __restrict__ out) {
    constexpr int CH = 18*512;
    __shared__ half_t wb[2*CH];
    __shared__ float bl[270];
    const int bid = blockIdx.x;
    const int cx  = bid & 7;
    const int kb  = bid >> 3;
    const int r   = ((kb >> 3) << 3) + cx;
    if (r >= NR) return;
    const int mt  = kb & 7;
    const int tid = threadIdx.x;
    if (tid < 140) bl[tid]       = b1[(size_t)r*140 + tid];
    if (tid < 84)  bl[140 + tid] = b2[(size_t)r*84  + tid];
    if (tid < 42)  bl[224 + tid] = b3[(size_t)r*42  + tid];
    if (tid < 4)   bl[266 + tid] = b4[(size_t)r*4   + tid];
    const int w = tid >> 6, l = tid & 63;
    const int g4 = ((l >> 4) & 3) * 4;
    const int mb0 = mt*8 + w*2;
    const size_t loff = (size_t)l * 8;

    auto stage1 = [&](int kc, half_t* buf) {
        const half_t* hs = w1h + ((size_t)r*7 + kc)*9*512;
        const half_t* ls = w1l + ((size_t)r*7 + kc)*9*512;
        #pragma unroll
        for (int p0 = 0; p0 < 3; ++p0) {
            const int p = w + p0*4;
            if (p < 9) {
                GLDS(hs + (size_t)p*512 + loff, buf + p*512);
                GLDS(ls + (size_t)p*512 + loff, buf + (9+p)*512);
            }
        }
    };
    auto stage2 = [&](int kc, half_t* buf) {
        const half_t* hs = w2h + ((size_t)r*5 + kc)*6*512;
        const half_t* ls = w2l + ((size_t)r*5 + kc)*6*512;
        #pragma unroll
        for (int p0 = 0; p0 < 2; ++p0) {
            const int p = w + p0*4;
            if (p < 6) {
                GLDS(hs + (size_t)p*512 + loff, buf + p*512);
                GLDS(ls + (size_t)p*512 + loff, buf + (6+p)*512);
            }
        }
    };
    auto stage3 = [&](int kc, half_t* buf) {
        const half_t* hs = w3h + ((size_t)r*3 + kc)*3*512;
        const half_t* ls = w3l + ((size_t)r*3 + kc)*3*512;
        if (w < 3) {
            GLDS(hs + (size_t)w*512 + loff, buf + w*512);
            GLDS(ls + (size_t)w*512 + loff, buf + (3+w)*512);
        }
    };

    // L1
    f16x8 bhv[2][2], blv[2][2];
    stage1(0, wb);
    #pragma unroll
    for (int mb = 0; mb < 2; ++mb) {
        const size_t bo = ((size_t)(mb0 + mb)*7 + 0)*512 + loff;
        bhv[0][mb] = *(const f16x8*)(g0h + bo);
        blv[0][mb] = *(const f16x8*)(g0l + bo);
    }
    __syncthreads();
    f32x4 a1[2][9] = {};
    #pragma unroll
    for (int kc = 0; kc < 7; ++kc) {
        const half_t* cur = wb + (kc & 1)*CH;
        if (kc < 6) {
            stage1(kc+1, wb + ((kc+1) & 1)*CH);
            #pragma unroll
            for (int mb = 0; mb < 2; ++mb) {
                const size_t bo = ((size_t)(mb0 + mb)*7 + kc + 1)*512 + loff;
                bhv[(kc+1)&1][mb] = *(const f16x8*)(g0h + bo);
                blv[(kc+1)&1][mb] = *(const f16x8*)(g0l + bo);
            }
        } else {
            stage2(0, wb + CH);
        }
        #pragma unroll
        for (int nf = 0; nf < 9; ++nf) {
            const f16x8 wh = *(const f16x8*)(cur + nf*512 + loff);
            const f16x8 wl = *(const f16x8*)(cur + (9+nf)*512 + loff);
            #pragma unroll
            for (int mb = 0; mb < 2; ++mb) {
                a1[mb][nf] = MFMA(wh, bhv[kc&1][mb], a1[mb][nf]);
                a1[mb][nf] = MFMA(wh, blv[kc&1][mb], a1[mb][nf]);
                a1[mb][nf] = MFMA(wl, bhv[kc&1][mb], a1[mb][nf]);
            }
        }
        __syncthreads();
    }
    f16x8 b2h[2][5], b2l[2][5];
    #pragma unroll
    for (int kc = 0; kc < 5; ++kc)
        #pragma unroll
        for (int h = 0; h < 2; ++h) {
            const int nf = kc*2 + h;
            #pragma unroll
            for (int mb = 0; mb < 2; ++mb)
                #pragma unroll
                for (int rr = 0; rr < 4; ++rr) {
                    float v = 0.f;
                    if (nf < 9) {
                        const int n = nf*16 + g4 + rr;
                        v = (n < 140) ? fmaxf(a1[mb][nf][rr] + bl[n], 0.f) : 0.f;
                    }
                    const half_t hi = (half_t)v;
                    const half_t lo = (half_t)(v - (float)hi);
                    b2h[mb][kc][h*4+rr] = hi;
                    b2l[mb][kc][h*4+rr] = lo;
                }
        }
    // L2
    f32x4 a2[2][6] = {};
    #pragma unroll
    for (int kc = 0; kc < 5; ++kc) {
        const half_t* cur = wb + (((kc+1) & 1))*CH;
        if (kc < 4) stage2(kc+1, wb + (kc & 1)*CH);
        else        stage3(0,    wb + (kc & 1)*CH);
        #pragma unroll
        for (int nf = 0; nf < 6; ++nf) {
            const f16x8 wh = *(const f16x8*)(cur + nf*512 + loff);
            const f16x8 wl = *(const f16x8*)(cur + (6+nf)*512 + loff);
            #pragma unroll
            for (int mb = 0; mb < 2; ++mb) {
                a2[mb][nf] = MFMA(wh, b2h[mb][kc], a2[mb][nf]);
                a2[mb][nf] = MFMA(wh, b2l[mb][kc], a2[mb][nf]);
                a2[mb][nf] = MFMA(wl, b2h[mb][kc], a2[mb][nf]);
            }
        }
        __syncthreads();
    }
    f16x8 b3h[2][3], b3l[2][3];
    #pragma unroll
    for (int kc = 0; kc < 3; ++kc)
        #pragma unroll
        for (int h = 0; h < 2; ++h) {
            const int nf = kc*2 + h;
            #pragma unroll
            for (int mb = 0; mb < 2; ++mb)
                #pragma unroll
                for (int rr = 0; rr < 4; ++rr) {
                    float v = 0.f;
                    if (nf < 6) {
                        const int n = nf*16 + g4 + rr;
                        v = (n < 84) ? fmaxf(a2[mb][nf][rr] + bl[140 + n], 0.f) : 0.f;
                    }
                    const half_t hi = (half_t)v;
                    const half_t lo = (half_t)(v - (float)hi);
                    b3h[mb][kc][h*4+rr] = hi;
                    b3l[mb][kc][h*4+rr] = lo;
                }
        }
    // L3
    f32x4 a3[2][3] = {};
    #pragma unroll
    for (int kc = 0; kc < 3; ++kc) {
        const half_t* cur = wb + (kc & 1)*CH;
        if (kc < 2) stage3(kc+1, wb + ((kc+1) & 1)*CH);
        #pragma unroll
        for (int nf = 0; nf < 3; ++nf) {
            const f16x8 wh = *(const f16x8*)(cur + nf*512 + loff);
            const f16x8 wl = *(const f16x8*)(cur + (3+nf)*512 + loff);
            #pragma unroll
            for (int mb = 0; mb < 2; ++mb) {
                a3[mb][nf] = MFMA(wh, b3h[mb][kc], a3[mb][nf]);
                a3[mb][nf] = MFMA(wh, b3l[mb][kc], a3[mb][nf]);
                a3[mb][nf] = MFMA(wl, b3h[mb][kc], a3[mb][nf]);
            }
        }
        __syncthreads();
    }
    f16x8 b4h[2][2], b4l[2][2];
    #pragma unroll
    for (int kc = 0; kc < 2; ++kc)
        #pragma unroll
        for (int h = 0; h < 2; ++h) {
            const int nf = kc*2 + h;
            #pragma unroll
            for (int mb = 0; mb < 2; ++mb)
                #pragma unroll
                for (int rr = 0; rr < 4; ++rr) {
                    float v = 0.f;
                    if (nf < 3) {
                        const int n = nf*16 + g4 + rr;
                        v = (n < 42) ? fmaxf(a3[mb][nf][rr] + bl[224 + n], 0.f) : 0.f;
                    }
                    const half_t hi = (half_t)v;
                    const half_t lo = (half_t)(v - (float)hi);
                    b4h[mb][kc][h*4+rr] = hi;
                    b4l[mb][kc][h*4+rr] = lo;
                }
        }
    // L4
    f32x4 a4[2] = {};
    #pragma unroll
    for (int kc = 0; kc < 2; ++kc) {
        const size_t wo = ((size_t)r*2 + kc)*512 + loff;
        const f16x8 wh = *(const f16x8*)(w4h + wo);
        const f16x8 wl = *(const f16x8*)(w4l + wo);
        #pragma unroll
        for (int mb = 0; mb < 2; ++mb) {
            a4[mb] = MFMA(wh, b4h[mb][kc], a4[mb]);
            a4[mb] = MFMA(wh, b4l[mb][kc], a4[mb]);
            a4[mb] = MFMA(wl, b4h[mb][kc], a4[mb]);
        }
    }
    if ((l >> 4) == 0) {
        #pragma unroll
        for (int mb = 0; mb < 2; ++mb) {
            const int b = (mb0 + mb)*16 + (l & 15);
            float4 o;
            o.x = a4[mb][0] + bl[266];
            o.y = a4[mb][1] + bl[267];
            o.z = a4[mb][2] + bl[268];
            o.w = a4[mb][3] + bl[269];
            *(float4*)(out + (size_t)b*400 + r*4) = o;
        }
    }
}

extern "C" void kernel_launch(void* const* d_in, const int* in_sizes, int n_in,
                              void* d_out, int out_size, void* d_ws, size_t ws_size,
                              hipStream_t stream) {
    const float* x    = (const float*)d_in[0];
    const float* c1w  = (const float*)d_in[1];
    const float* c1b  = (const float*)d_in[2];
    const float* c2w  = (const float*)d_in[3];
    const float* c2b  = (const float*)d_in[4];
    const float* c3w  = (const float*)d_in[5];
    const float* c3b  = (const float*)d_in[6];
    const float* fc1w = (const float*)d_in[7];
    const float* fc1b = (const float*)d_in[8];
    const float* fc2w = (const float*)d_in[9];
    const float* fc2b = (const float*)d_in[10];
    const float* h1w  = (const float*)d_in[11];
    const float* h1b  = (const float*)d_in[12];
    const float* h2w  = (const float*)d_in[13];
    const float* h2b  = (const float*)d_in[14];
    const float* h3w  = (const float*)d_in[15];
    const float* h3b  = (const float*)d_in[16];
    const float* h4w  = (const float*)d_in[17];
    const float* h4b  = (const float*)d_in[18];
    float* out = (float*)d_out;

    char* ws = (char*)d_ws;
    size_t o = 0;
    float* t2 = (float*)(ws + o); o += (size_t)NB*4*484*4;
    float* t3 = (float*)(ws + o); o += (size_t)NB*200*4;
    float* f1 = (float*)(ws + o); o += (size_t)NB*400*4;
    half_t* g0h = (half_t*)(ws + o); o += (size_t)64*7*512*2;
    half_t* g0l = (half_t*)(ws + o); o += (size_t)64*7*512*2;
    half_t* w1h = (half_t*)(ws + o); o += (size_t)NR*7*9*512*2;
    half_t* w1l = (half_t*)(ws + o); o += (size_t)NR*7*9*512*2;
    half_t* w2h = (half_t*)(ws + o); o += (size_t)NR*5*6*512*2;
    half_t* w2l = (half_t*)(ws + o); o += (size_t)NR*5*6*512*2;
    half_t* w3h = (half_t*)(ws + o); o += (size_t)NR*3*3*512*2;
    half_t* w3l = (half_t*)(ws + o); o += (size_t)NR*3*3*512*2;
    half_t* w4h = (half_t*)(ws + o); o += (size_t)NR*2*1*512*2;
    half_t* w4l = (half_t*)(ws + o); o += (size_t)NR*2*1*512*2;
    float* wp1 = (float*)(ws + o); o += 64*4;
    float* wp2 = (float*)(ws + o); o += 896*4;

    wpack_k<<<1, 256, 0, stream>>>(c1w, c2w, wp1, wp2);
    conv12_k<<<NB*4, 256, 0, stream>>>(x, wp1, c1b, wp2, c2b, t2);
    conv3_k<<<NB, 256, 0, stream>>>(t2, c3w, c3b, t3);
    fc1_k<<<dim3(7, 8), 256, 0, stream>>>(t3, fc1w, fc1b, f1);
    fc2ws_k<<<32 + 1700, 256, 0, stream>>>(f1, fc2w, fc2b, g0h, g0l,
        h1w, h2w, h3w, h4w, w1h, w1l, w2h, w2l, w3h, w3l, w4h, w4l);
    head_k<<<832, 256, 0, stream>>>(
        g0h, g0l, w1h, w1l, w2h, w2l, w3h, w3l, w4h, w4l,
        h1b, h2b, h3b, h4b, out);

    (void)in_sizes; (void)n_in; (void)out_size; (void)ws_size;
}